// Round 7
// baseline (1091.638 us; speedup 1.0000x reference)
//
#include <hip/hip_runtime.h>
#include <hip/hip_cooperative_groups.h>

// GCN 2-layer. R6: bf16-MFMA GEMMs (no LDS, operand-swap epilogue). R9:
// atomic-free CSR (two-level bucket sort; device fetch-add ~24 Gops/s wall).
// R10: scalar edge fetch in gathers. R11 (reverted): slab slicing — FETCH
// 193->62MB but 8x metadata cost; 256B-random-row gather ~3.8 TB/s = wall.
// R12: chain consolidation (11 launches). R13: whole CSR build fused into
// ONE cooperative kernel (5 grid.syncs): scan chunk data held in registers
// across syncs; bucket phase writes row_ptr/dinv directly (cnt + cnt-scan
// deleted) and parks rp/dinv slices in LDS; build_ew now edge-parallel with
// LDS binary-search node lookup -> coalesced ew writes (was scattered 4B).
// Runtime fallback to the R12 7-kernel chain if coop launch is refused.
// 4B edge payload src(17b)|ws15. Features bf16-pair packed.

typedef unsigned int u32;
using bfrag = __attribute__((ext_vector_type(8))) short;   // 8 bf16 (4 VGPRs)
using f4    = __attribute__((ext_vector_type(4))) float;   // 4 fp32 acc

__device__ inline u32 pack_bf16(float a, float b) {
    u32 ua = __float_as_uint(a);
    u32 ub = __float_as_uint(b);
    ua += 0x7fffu + ((ua >> 16) & 1u);   // RNE
    ub += 0x7fffu + ((ub >> 16) & 1u);
    return (ua >> 16) | (ub & 0xffff0000u);
}
__device__ inline float bf_lo(u32 v) { return __uint_as_float(v << 16); }
__device__ inline float bf_hi(u32 v) { return __uint_as_float(v & 0xffff0000u); }

// w in [2^-8, 1] -> 15 bits: ws = (bits(w) + rnd - 0x3B800000) >> 12.
__device__ inline u32 pack_w(float w) {
    u32 b = __float_as_uint(w) + 0x800u;       // round mantissa at 11 bits
    if (b < 0x3B800000u) b = 0x3B800000u;      // clamp to 2^-8 (unreachable)
    if (b > 0x3F800000u) b = 0x3F800000u;      // clamp to 1.0
    return (b - 0x3B800000u) >> 12;            // 15 bits
}
__device__ inline float dec_w(u32 e) {
    return __uint_as_float(((e & 0x7fffu) << 12) + 0x3B800000u);
}

__device__ inline bfrag as_bfrag(uint4 v) {
    union { uint4 u; bfrag b; } x; x.u = v; return x.b;
}

__device__ inline void prep_w_chunk(int idx, const float* __restrict__ W1,
                                    const float* __restrict__ W2,
                                    u32* __restrict__ W1t, u32* __restrict__ W2t) {
    if (idx < 128 * 64) {
        int nr = idx >> 6, kd = idx & 63;
        W1t[idx] = pack_bf16(W1[(2 * kd) * 128 + nr], W1[(2 * kd + 1) * 128 + nr]);
    } else if (idx < 128 * 64 + 64 * 64) {
        int i = idx - 128 * 64;
        int nr = i >> 6, kd = i & 63;
        W2t[i] = pack_bf16(W2[(2 * kd) * 64 + nr], W2[(2 * kd + 1) * 64 + nr]);
    }
}

// ================= cooperative CSR build (one kernel) =================
// grid = NB3 blocks x 256 threads. Phases:
//  1  count_bins -> bco[bin][blk]  (+ prep_w on blocks 0..47)
//  2a chunk sums of bco (1024/chunk, data kept in registers)
//  2c exclusive-prefix apply (block offset self-computed from bsum)
//  3  scatter into bin-block ranges (LDS cursors) -> tmp2
//  4  per-bin 256-way hist + LDS scan -> row_ptr/dinv direct; scatter tmp3
//  5  build ew: edge-parallel, LDS binary-search node lookup, coalesced.
__global__ __launch_bounds__(256) void csr_coop(
    const int* __restrict__ src, const int* __restrict__ dst,
    int* __restrict__ bco, int* __restrict__ bsum,
    u32* __restrict__ tmp2, u32* __restrict__ tmp3,
    int* __restrict__ row_ptr, float* __restrict__ dinv, u32* __restrict__ ew,
    const float* __restrict__ W1, const float* __restrict__ W2,
    u32* __restrict__ W1t, u32* __restrict__ W2t,
    int E, int n, int nbin, int nb3, int M, int MB)
{
    cooperative_groups::grid_group grid = cooperative_groups::this_grid();
    const int b    = blockIdx.x;
    const int t    = threadIdx.x;
    const int lane = t & 63;
    const int wid  = t >> 6;

    __shared__ int   sh_cur[512];   // phase1 hist / phase3 cursors
    __shared__ int   sh_h4[256];    // phase4 hist
    __shared__ int   sh_c4[256];    // phase4 cursors
    __shared__ int   sh_w[16];      // reduce/scan scratch
    __shared__ int   sh_rp[257];    // phase4->5 row_ptr slice
    __shared__ float sh_di[256];    // phase4->5 dinv slice
    __shared__ int   sh_b;          // broadcast

    // ---- phase 1: coarse histogram (dst>>8) ----
    {
        for (int i = t; i < nbin; i += 256) sh_cur[i] = 0;
        __syncthreads();
        const int base = b * 2048 + t;
#pragma unroll
        for (int k = 0; k < 8; ++k) {
            int e = base + k * 256;
            if (e < E) atomicAdd(&sh_cur[dst[e] >> 8], 1);
        }
        __syncthreads();
        for (int i = t; i < nbin; i += 256)
            bco[(size_t)i * nb3 + b] = sh_cur[i];
        if (b == 0 && t == 0) bco[M] = E;
        if (b < 48) prep_w_chunk(b * 256 + t, W1, W2, W1t, W2t);
    }
    __threadfence();
    grid.sync();

    // ---- phase 2a: chunk sums (chunk b covers bco[b*1024 .. +1024)) ----
    int v0 = 0, v1 = 0, v2 = 0, v3 = 0;
    if (b < MB) {
        const int i0 = b * 1024 + t * 4;
        if (i0 + 3 < M) {
            int4 q = *(const int4*)(bco + i0);
            v0 = q.x; v1 = q.y; v2 = q.z; v3 = q.w;
        } else {
            if (i0     < M) v0 = bco[i0];
            if (i0 + 1 < M) v1 = bco[i0 + 1];
            if (i0 + 2 < M) v2 = bco[i0 + 2];
            if (i0 + 3 < M) v3 = bco[i0 + 3];
        }
        int s = v0 + v1 + v2 + v3;
#pragma unroll
        for (int off = 32; off > 0; off >>= 1) s += __shfl_down(s, off);
        if (lane == 0) sh_w[wid] = s;
        __syncthreads();
        if (t == 0) bsum[b] = sh_w[0] + sh_w[1] + sh_w[2] + sh_w[3];
    }
    __threadfence();
    grid.sync();

    // ---- phase 2c: apply exclusive prefix (chunk data still in regs) ----
    if (b < MB) {
        int pv = 0;
        if (t < b)        pv += bsum[t];
        if (t + 256 < b)  pv += bsum[t + 256];
#pragma unroll
        for (int off = 32; off > 0; off >>= 1) pv += __shfl_down(pv, off);
        if (lane == 0) sh_w[wid] = pv;
        __syncthreads();
        if (t == 0) sh_b = sh_w[0] + sh_w[1] + sh_w[2] + sh_w[3];
        __syncthreads();
        const int blockoff = sh_b;
        const int tv = v0 + v1 + v2 + v3;
        int x = tv;
#pragma unroll
        for (int off = 1; off < 64; off <<= 1) {
            int u = __shfl_up(x, off);
            if (lane >= off) x += u;
        }
        if (lane == 63) sh_w[wid] = x;
        __syncthreads();
        int woff = 0;
        for (int w2 = 0; w2 < wid; ++w2) woff += sh_w[w2];
        int p = blockoff + woff + (x - tv);
        const int i0 = b * 1024 + t * 4;
        if (i0     < M) bco[i0]     = p;
        if (i0 + 1 < M) bco[i0 + 1] = p + v0;
        if (i0 + 2 < M) bco[i0 + 2] = p + v0 + v1;
        if (i0 + 3 < M) bco[i0 + 3] = p + v0 + v1 + v2;
    }
    __threadfence();
    grid.sync();

    // ---- phase 3: scatter edges into bin-block reserved ranges ----
    {
        for (int i = t; i < nbin; i += 256)
            sh_cur[i] = bco[(size_t)i * nb3 + b];
        __syncthreads();
        const int base = b * 2048 + t;
#pragma unroll
        for (int k = 0; k < 8; ++k) {
            int e = base + k * 256;
            if (e < E) {
                int d = dst[e];
                int pos = atomicAdd(&sh_cur[d >> 8], 1);
                tmp2[pos] = ((u32)(d & 255) << 17) | (u32)src[e];
            }
        }
    }
    __threadfence();
    grid.sync();

    // ---- phase 4: per-bin hist + scan -> row_ptr/dinv; scatter tmp3 ----
    int binbeg = 0, binend = 0;
    if (b < nbin) {
        binbeg = bco[(size_t)b * nb3];
        binend = bco[(size_t)(b + 1) * nb3];   // bco[M] = E for last bin
        sh_h4[t] = 0;
        __syncthreads();
        for (int i = binbeg + t; i < binend; i += 256)
            atomicAdd(&sh_h4[tmp2[i] >> 17], 1);
        __syncthreads();
        int v = sh_h4[t];
        int x = v;
#pragma unroll
        for (int off = 1; off < 64; off <<= 1) {
            int u = __shfl_up(x, off);
            if (lane >= off) x += u;
        }
        if (lane == 63) sh_w[wid] = x;
        __syncthreads();
        int woff = 0;
        for (int w2 = 0; w2 < wid; ++w2) woff += sh_w[w2];
        const int rp = binbeg + woff + (x - v);
        sh_rp[t] = rp;
        if (t == 255) sh_rp[256] = binend;
        sh_c4[t] = rp;
        const float di = rsqrtf((float)v + 1.0f);
        sh_di[t] = di;
        const int d = b * 256 + t;
        if (d < n) { row_ptr[d] = rp; dinv[d] = di; }
        if (b == 0 && t == 0) row_ptr[n] = E;
        __syncthreads();
        for (int i = binbeg + t; i < binend; i += 256) {
            u32 r = tmp2[i];
            int pos = atomicAdd(&sh_c4[r >> 17], 1);
            tmp3[pos] = r & 0x1ffffu;   // src
        }
    }
    __threadfence();
    grid.sync();

    // ---- phase 5: build ew (coalesced; LDS binary-search node lookup) ----
    if (b < nbin) {
        for (int i = binbeg + t; i < binend; i += 256) {
            u32 s = tmp3[i];
            int lo = 0, hi = 255;
#pragma unroll
            for (int st = 0; st < 8; ++st) {
                int mid = (lo + hi + 1) >> 1;
                if (sh_rp[mid] <= i) lo = mid; else hi = mid - 1;
            }
            float w = dinv[s] * sh_di[lo];
            ew[i] = (s << 15) | pack_w(w);
        }
    }
}

// ================= fallback chain (R12, used only if coop refused) ========

__global__ __launch_bounds__(256) void count_bins_pw(const int* __restrict__ dst,
                                                     int* __restrict__ bc,
                                                     int E, int nbin, int nb3, int M,
                                                     const float* __restrict__ W1,
                                                     const float* __restrict__ W2,
                                                     u32* __restrict__ W1t,
                                                     u32* __restrict__ W2t) {
    __shared__ int hist[512];
    if (blockIdx.x >= (unsigned)nb3) {
        prep_w_chunk((blockIdx.x - nb3) * 256 + threadIdx.x, W1, W2, W1t, W2t);
        return;
    }
    if (blockIdx.x == 0 && threadIdx.x == 0) bc[M] = E;
    for (int t = threadIdx.x; t < nbin; t += 256) hist[t] = 0;
    __syncthreads();
    const int base = blockIdx.x * 2048 + threadIdx.x;
#pragma unroll
    for (int k = 0; k < 8; ++k) {
        int e = base + k * 256;
        if (e < E) atomicAdd(&hist[dst[e] >> 8], 1);
    }
    __syncthreads();
    for (int t = threadIdx.x; t < nbin; t += 256)
        bc[(size_t)t * nb3 + blockIdx.x] = hist[t];
}

__global__ __launch_bounds__(1024) void scan_reduce_g(const int* __restrict__ a,
                                                      int* __restrict__ bsum, int M) {
    __shared__ int wsum[16];
    int i = blockIdx.x * 1024 + threadIdx.x;
    int v = (i < M) ? a[i] : 0;
#pragma unroll
    for (int off = 32; off > 0; off >>= 1) v += __shfl_down(v, off);
    const int lane = threadIdx.x & 63;
    const int wid  = threadIdx.x >> 6;
    if (lane == 0) wsum[wid] = v;
    __syncthreads();
    if (threadIdx.x < 16) {
        int s = wsum[threadIdx.x];
#pragma unroll
        for (int off = 8; off > 0; off >>= 1) s += __shfl_down(s, off);
        if (threadIdx.x == 0) bsum[blockIdx.x] = s;
    }
}

__global__ __launch_bounds__(1024) void scan_apply_g2(int* __restrict__ a,
                                                      const int* __restrict__ bsum,
                                                      int nb, int M) {
    __shared__ int wsum[16];
    __shared__ int base_s;
    const int lane = threadIdx.x & 63;
    const int wid  = threadIdx.x >> 6;
    int pv = 0;
    for (int t = threadIdx.x; t < (int)blockIdx.x; t += 1024) pv += bsum[t];
#pragma unroll
    for (int off = 32; off > 0; off >>= 1) pv += __shfl_down(pv, off);
    if (lane == 0) wsum[wid] = pv;
    __syncthreads();
    if (threadIdx.x == 0) {
        int s = 0;
#pragma unroll
        for (int w = 0; w < 16; ++w) s += wsum[w];
        base_s = s;
    }
    __syncthreads();
    const int boff = base_s;
    int i = blockIdx.x * 1024 + threadIdx.x;
    int v = (i < M) ? a[i] : 0;
    int x = v;
#pragma unroll
    for (int off = 1; off < 64; off <<= 1) {
        int t = __shfl_up(x, off);
        if (lane >= off) x += t;
    }
    if (lane == 63) wsum[wid] = x;
    __syncthreads();
    if (wid == 0 && lane < 16) {
        int w = wsum[lane];
#pragma unroll
        for (int off = 1; off < 16; off <<= 1) {
            int t = __shfl_up(w, off);
            if (lane >= off) w += t;
        }
        wsum[lane] = w;
    }
    __syncthreads();
    int wave_excl = (wid == 0) ? 0 : wsum[wid - 1];
    if (i < M) a[i] = boff + wave_excl + (x - v);
}

__global__ __launch_bounds__(1024) void scan_apply_cnt2(const int* __restrict__ cnt,
                                                        const int* __restrict__ bco,
                                                        int* __restrict__ row_ptr,
                                                        float* __restrict__ dinv,
                                                        int n, int nb3, int E) {
    __shared__ int wsum[16];
    const int lane = threadIdx.x & 63;
    const int wid  = threadIdx.x >> 6;
    const int boff = bco[(size_t)(4 * blockIdx.x) * nb3];
    int i = blockIdx.x * 1024 + threadIdx.x;
    int v = (i < n) ? cnt[i] : 0;
    int x = v;
#pragma unroll
    for (int off = 1; off < 64; off <<= 1) {
        int t = __shfl_up(x, off);
        if (lane >= off) x += t;
    }
    if (lane == 63) wsum[wid] = x;
    __syncthreads();
    if (wid == 0 && lane < 16) {
        int w = wsum[lane];
#pragma unroll
        for (int off = 1; off < 16; off <<= 1) {
            int t = __shfl_up(w, off);
            if (lane >= off) w += t;
        }
        wsum[lane] = w;
    }
    __syncthreads();
    int wave_excl = (wid == 0) ? 0 : wsum[wid - 1];
    if (i < n) {
        row_ptr[i] = boff + wave_excl + (x - v);
        dinv[i]    = rsqrtf((float)v + 1.0f);
    }
    if (blockIdx.x == 0 && threadIdx.x == 0) row_ptr[n] = E;
}

__global__ __launch_bounds__(256) void scatter_bins(const int* __restrict__ src,
                                                    const int* __restrict__ dst,
                                                    const int* __restrict__ offs,
                                                    u32* __restrict__ tmp,
                                                    int E, int nbin, int nb3) {
    __shared__ int cur[512];
    for (int t = threadIdx.x; t < nbin; t += 256)
        cur[t] = offs[(size_t)t * nb3 + blockIdx.x];
    __syncthreads();
    const int base = blockIdx.x * 2048 + threadIdx.x;
#pragma unroll
    for (int k = 0; k < 8; ++k) {
        int e = base + k * 256;
        if (e < E) {
            int d = dst[e];
            int pos = atomicAdd(&cur[d >> 8], 1);
            tmp[pos] = ((u32)(d & 255) << 17) | (u32)src[e];
        }
    }
}

__global__ __launch_bounds__(256) void bucket_csr(const u32* __restrict__ tmp,
                                                  const int* __restrict__ offs,
                                                  u32* __restrict__ tmp3,
                                                  int* __restrict__ cnt,
                                                  int n, int nb3) {
    __shared__ int hist[256];
    __shared__ int cur[256];
    __shared__ int wtot[4];
    const int b   = blockIdx.x;
    const int beg = offs[(size_t)b * nb3];
    const int end = offs[(size_t)(b + 1) * nb3];
    hist[threadIdx.x] = 0;
    __syncthreads();
    for (int i = beg + threadIdx.x; i < end; i += 256)
        atomicAdd(&hist[tmp[i] >> 17], 1);
    __syncthreads();
    const int lane = threadIdx.x & 63;
    const int wid  = threadIdx.x >> 6;
    int v = hist[threadIdx.x];
    int x = v;
#pragma unroll
    for (int off = 1; off < 64; off <<= 1) {
        int t = __shfl_up(x, off);
        if (lane >= off) x += t;
    }
    if (lane == 63) wtot[wid] = x;
    __syncthreads();
    int wbase = 0;
    for (int w = 0; w < wid; ++w) wbase += wtot[w];
    cur[threadIdx.x] = beg + wbase + x - v;
    int d = b * 256 + threadIdx.x;
    if (d < n) cnt[d] = v;
    __syncthreads();
    for (int i = beg + threadIdx.x; i < end; i += 256) {
        u32 r = tmp[i];
        int pos = atomicAdd(&cur[r >> 17], 1);
        tmp3[pos] = r & 0x1ffffu;
    }
}

__global__ __launch_bounds__(256) void build_ew(const u32* __restrict__ tmp3,
                                                const int* __restrict__ row_ptr,
                                                const float* __restrict__ dinv,
                                                u32* __restrict__ ew, int n) {
    int d = blockIdx.x * 256 + threadIdx.x;
    if (d >= n) return;
    float dd = dinv[d];
    int beg = row_ptr[d], end = row_ptr[d + 1];
    for (int i = beg; i < end; ++i) {
        u32 s = tmp3[i];
        ew[i] = (s << 15) | pack_w(dinv[s] * dd);
    }
}

// ---------------- GEMM ----------------

// C[n][OUT] bf16-packed = A[n][128] @ W[128][OUT], via 16x16x32 bf16 MFMA.
// No LDS. Wave handles 32 rows (2 m-frags). Operand swap: mfma(w_frag, a_frag)
// -> D tile = C^T layout: C-row = lane&15, C-col = nt*16 + quad*4 + reg, so
// each lane holds 4 consecutive C-cols -> one uint2 store per tile.
// ABF: A is bf16-pair packed [n][64] dwords; else fp32 [n][128].
template <int OUT, bool ABF>
__global__ __launch_bounds__(256) void gemm_mfma(const void* __restrict__ Ap,
                                                 const u32* __restrict__ Wt,
                                                 u32* __restrict__ C, int n) {
    constexpr int NT = OUT / 16;
    const int lane = threadIdx.x & 63;
    const int wv   = threadIdx.x >> 6;
    const int r15  = lane & 15;
    const int quad = lane >> 4;
    const int rowbase = blockIdx.x * 128 + wv * 32;

    bfrag af[2][4];
#pragma unroll
    for (int mi = 0; mi < 2; ++mi) {
        int row = rowbase + mi * 16 + r15;
        row = (row < n) ? row : (n - 1);
        if constexpr (ABF) {
            const u32* ar = (const u32*)Ap + (size_t)row * 64 + quad * 4;
#pragma unroll
            for (int ks = 0; ks < 4; ++ks)
                af[mi][ks] = as_bfrag(*(const uint4*)(ar + ks * 16));
        } else {
            const float* arf = (const float*)Ap + (size_t)row * 128 + quad * 8;
#pragma unroll
            for (int ks = 0; ks < 4; ++ks) {
                float4 v0 = *(const float4*)(arf + ks * 32);
                float4 v1 = *(const float4*)(arf + ks * 32 + 4);
                uint4 p;
                p.x = pack_bf16(v0.x, v0.y);
                p.y = pack_bf16(v0.z, v0.w);
                p.z = pack_bf16(v1.x, v1.y);
                p.w = pack_bf16(v1.z, v1.w);
                af[mi][ks] = as_bfrag(p);
            }
        }
    }

    f4 acc[2][NT];
#pragma unroll
    for (int mi = 0; mi < 2; ++mi)
#pragma unroll
        for (int nt = 0; nt < NT; ++nt) acc[mi][nt] = (f4)0.0f;

#pragma unroll
    for (int nt = 0; nt < NT; ++nt) {
        const u32* wr = Wt + (size_t)(nt * 16 + r15) * 64 + quad * 4;
#pragma unroll
        for (int ks = 0; ks < 4; ++ks) {
            bfrag bf = as_bfrag(*(const uint4*)(wr + ks * 16));
            acc[0][nt] = __builtin_amdgcn_mfma_f32_16x16x32_bf16(bf, af[0][ks], acc[0][nt], 0, 0, 0);
            acc[1][nt] = __builtin_amdgcn_mfma_f32_16x16x32_bf16(bf, af[1][ks], acc[1][nt], 0, 0, 0);
        }
    }

#pragma unroll
    for (int mi = 0; mi < 2; ++mi) {
        int row = rowbase + mi * 16 + r15;
        if (row < n) {
            u32* cp = C + (size_t)row * (OUT / 2);
#pragma unroll
            for (int nt = 0; nt < NT; ++nt) {
                uint2 p;
                p.x = pack_bf16(acc[mi][nt][0], acc[mi][nt][1]);
                p.y = pack_bf16(acc[mi][nt][2], acc[mi][nt][3]);
                *(uint2*)(cp + nt * 8 + quad * 2) = p;
            }
        }
    }
}

// ---------------- gathers: scalar edge fetch (R10 structure) ----------------

__global__ __launch_bounds__(256) void gather128(const u32* __restrict__ h,
                                                 const float* __restrict__ dinv,
                                                 const int* __restrict__ row_ptr,
                                                 const u32* __restrict__ ew,
                                                 const float* __restrict__ bias,
                                                 u32* __restrict__ outp, int n) {
    const int lane = threadIdx.x & 63;
    int node = blockIdx.x * 4 + (threadIdx.x >> 6);
    if (node >= n) return;
    node = __builtin_amdgcn_readfirstlane(node);

    const float dd  = dinv[node];
    const int   beg = __builtin_amdgcn_readfirstlane(row_ptr[node]);
    const int   end = __builtin_amdgcn_readfirstlane(row_ptr[node + 1]);

    u32 sv = h[(size_t)node * 64 + lane];
    float2 b = ((const float2*)bias)[lane];
    float acc0 = fmaf(bf_lo(sv) * dd, dd, b.x);
    float acc1 = fmaf(bf_hi(sv) * dd, dd, b.y);

    int j = beg;
    for (; j + 16 <= end; j += 16) {
        u32 ep[16];
#pragma unroll
        for (int k = 0; k < 16; ++k) ep[k] = ew[j + k];        // s_load (merged)
        u32 v[16];
#pragma unroll
        for (int k = 0; k < 16; ++k)
            v[k] = h[((size_t)(ep[k] >> 15) << 6) + lane];     // saddr + lane
#pragma unroll
        for (int k = 0; k < 16; ++k) {
            float wf = dec_w(ep[k]);                           // SALU decode
            acc0 = fmaf(wf, bf_lo(v[k]), acc0);
            acc1 = fmaf(wf, bf_hi(v[k]), acc1);
        }
    }
    for (; j < end; j += 8) {
        const int cnt = end - j;                               // 1..15 (SGPR)
        u32 ep[8];
#pragma unroll
        for (int k = 0; k < 8; ++k) {
            int c = j + k;
            ep[k] = ew[(c < end) ? c : end - 1];               // scalar clamp
        }
        u32 v[8];
#pragma unroll
        for (int k = 0; k < 8; ++k)
            v[k] = h[((size_t)(ep[k] >> 15) << 6) + lane];     // pads: L1-hot row
#pragma unroll
        for (int k = 0; k < 8; ++k) {
            float wf = (k < cnt) ? dec_w(ep[k]) : 0.0f;        // scalar select
            acc0 = fmaf(wf, bf_lo(v[k]), acc0);
            acc1 = fmaf(wf, bf_hi(v[k]), acc1);
        }
    }

    // relu + bf16 pack (relu commutes with RNE quantization)
    outp[(size_t)node * 64 + lane] = pack_bf16(fmaxf(acc0, 0.0f), fmaxf(acc1, 0.0f));
}

__global__ __launch_bounds__(256) void gather64(const u32* __restrict__ h,
                                                const float* __restrict__ dinv,
                                                const int* __restrict__ row_ptr,
                                                const u32* __restrict__ ew,
                                                const float* __restrict__ bias,
                                                float* __restrict__ outp, int n) {
    const int lane   = threadIdx.x & 63;
    const int lane32 = lane & 31;
    const int sub    = lane >> 5;
    int node = blockIdx.x * 4 + (threadIdx.x >> 6);
    if (node >= n) return;
    node = __builtin_amdgcn_readfirstlane(node);

    const int beg = __builtin_amdgcn_readfirstlane(row_ptr[node]);
    const int end = __builtin_amdgcn_readfirstlane(row_ptr[node + 1]);

    float acc0 = 0.0f, acc1 = 0.0f;
    if (sub == 0) {
        const float dd = dinv[node];
        u32 sv = h[(size_t)node * 32 + lane32];
        float2 b = ((const float2*)bias)[lane32];
        acc0 = fmaf(bf_lo(sv) * dd, dd, b.x);
        acc1 = fmaf(bf_hi(sv) * dd, dd, b.y);
    }

    int j = beg;
    for (; j + 16 <= end; j += 16) {
        u32 ep[16];
#pragma unroll
        for (int k = 0; k < 16; ++k) ep[k] = ew[j + k];        // s_load (merged)
        u32 v[8]; float wl[8];
#pragma unroll
        for (int p = 0; p < 8; ++p) {
            u32 e0 = ep[2 * p], e1 = ep[2 * p + 1];
            u32 so = sub ? (e1 >> 15) : (e0 >> 15);            // cndmask
            wl[p]  = sub ? dec_w(e1) : dec_w(e0);              // cndmask
            v[p]   = h[((size_t)so << 5) + lane32];
        }
#pragma unroll
        for (int p = 0; p < 8; ++p) {
            acc0 = fmaf(wl[p], bf_lo(v[p]), acc0);
            acc1 = fmaf(wl[p], bf_hi(v[p]), acc1);
        }
    }
    for (; j < end; j += 8) {
        const int cnt = end - j;                               // 1..15 (SGPR)
        u32 ep[8];
#pragma unroll
        for (int k = 0; k < 8; ++k) {
            int c = j + k;
            ep[k] = ew[(c < end) ? c : end - 1];               // scalar clamp
        }
        u32 v[4]; float wl[4];
#pragma unroll
        for (int p = 0; p < 4; ++p) {
            u32 e0 = ep[2 * p], e1 = ep[2 * p + 1];
            float w0 = (2 * p     < cnt) ? dec_w(e0) : 0.0f;   // scalar select
            float w1 = (2 * p + 1 < cnt) ? dec_w(e1) : 0.0f;
            u32 so = sub ? (e1 >> 15) : (e0 >> 15);
            wl[p]  = sub ? w1 : w0;
            v[p]   = h[((size_t)so << 5) + lane32];            // pads: L1-hot row
        }
#pragma unroll
        for (int p = 0; p < 4; ++p) {
            acc0 = fmaf(wl[p], bf_lo(v[p]), acc0);
            acc1 = fmaf(wl[p], bf_hi(v[p]), acc1);
        }
    }

    acc0 += __shfl_xor(acc0, 32);
    acc1 += __shfl_xor(acc1, 32);
    if (sub == 0)
        ((float2*)(outp + (size_t)node * 64))[lane32] = make_float2(acc0, acc1);
}

extern "C" void kernel_launch(void* const* d_in, const int* in_sizes, int n_in,
                              void* d_out, int out_size, void* d_ws, size_t ws_size,
                              hipStream_t stream) {
    const float* x  = (const float*)d_in[0];
    const int*   ei = (const int*)d_in[1];
    const float* W1 = (const float*)d_in[2];
    const float* b1 = (const float*)d_in[3];
    const float* W2 = (const float*)d_in[4];
    const float* b2 = (const float*)d_in[5];
    float*       out = (float*)d_out;

    int n = in_sizes[0] / 128;   // 100000
    int E = in_sizes[1] / 2;     // 1600000
    const int* srcv = ei;
    const int* dstv = ei + E;

    const int NP = 102400;
    u32* wsd = (u32*)d_ws;
    float* dinv    = (float*)wsd;                        // NP
    int*   row_ptr = (int*)(wsd + NP);                   // NP
    u32*   ew      = wsd + 2 * (size_t)NP;               // E
    u32*   h1u     = ew + E;                             // n*64 (gemm1 C / gather128 in)
    u32*   agg1b   = h1u + (size_t)n * 64;               // n*64 (gather128 out / gemm2 A)
    u32*   W1t     = agg1b + (size_t)n * 64;             // 8192
    u32*   W2t     = W1t + 8192;                         // 4096
    u32*   h2u     = h1u;                                // gemm2 C: n*32, reuses h1u

    // CSR scratch — overlaid on h1u (dead until gemm1 writes it):
    int*   cnt  = (int*)h1u;                             // n (fallback only)
    int*   bco  = (int*)(h1u + 131072);                  // M+1
    u32*   tmp2 = h1u + 524288;                          // E
    u32*   tmp3 = tmp2 + (size_t)E;                      // E
    int*   bsum = (int*)(h1u + 4000000);                 // 512

    int NBIN = (n + 255) >> 8;          // 391
    int NB3  = (E + 2047) / 2048;       // 782
    int M    = NBIN * NB3;              // 305,762
    int MB   = (M + 1023) / 1024;       // 299
    const int NB = (n + 1023) / 1024;   // 98

    // --- CSR build: one cooperative kernel (fallback: R12 chain) ---
    void* cargs[] = {
        (void*)&srcv, (void*)&dstv, (void*)&bco, (void*)&bsum,
        (void*)&tmp2, (void*)&tmp3, (void*)&row_ptr, (void*)&dinv, (void*)&ew,
        (void*)&W1, (void*)&W2, (void*)&W1t, (void*)&W2t,
        (void*)&E, (void*)&n, (void*)&NBIN, (void*)&NB3, (void*)&M, (void*)&MB
    };
    hipError_t cerr = hipLaunchCooperativeKernel((const void*)csr_coop,
                                                 dim3(NB3), dim3(256),
                                                 cargs, 0, stream);
    if (cerr != hipSuccess) {
        count_bins_pw<<<NB3 + 48, 256, 0, stream>>>(dstv, bco, E, NBIN, NB3, M,
                                                    W1, W2, W1t, W2t);
        scan_reduce_g<<<MB, 1024, 0, stream>>>(bco, bsum, M);
        scan_apply_g2<<<MB, 1024, 0, stream>>>(bco, bsum, MB, M);
        scatter_bins<<<NB3, 256, 0, stream>>>(srcv, dstv, bco, tmp2, E, NBIN, NB3);
        bucket_csr<<<NBIN, 256, 0, stream>>>(tmp2, bco, tmp3, cnt, n, NB3);
        scan_apply_cnt2<<<NB, 1024, 0, stream>>>(cnt, bco, row_ptr, dinv, n, NB3, E);
        build_ew<<<(n + 255) / 256, 256, 0, stream>>>(tmp3, row_ptr, dinv, ew, n);
    }

    const int gblocks = (n + 127) / 128;  // 782
    // --- layer 1 ---
    gemm_mfma<128, false><<<gblocks, 256, 0, stream>>>(x, W1t, h1u, n);
    gather128<<<(n + 3) / 4, 256, 0, stream>>>(h1u, dinv, row_ptr, ew, b1, agg1b, n);

    // --- layer 2 ---
    gemm_mfma<64, true><<<gblocks, 256, 0, stream>>>(agg1b, W2t, h2u, n);
    gather64<<<(n + 3) / 4, 256, 0, stream>>>(h2u, dinv, row_ptr, ew, b2, out, n);
}

// Round 8
// 294.065 us; speedup vs baseline: 3.7122x; 3.7122x over previous
//
#include <hip/hip_runtime.h>

// GCN 2-layer. R6: bf16-MFMA GEMMs (no LDS, operand-swap epilogue). R9:
// atomic-free CSR (two-level bucket sort; device fetch-add ~24 Gops/s wall).
// R10: scalar edge fetch in gathers. R11 (reverted): slab slicing — FETCH
// 193->62MB but 8x metadata cost. R13 (reverted): cooperative-kernel CSR —
// grid.sync() with 782 blocks cost ~800us. R14: kept R13's sync-free wins:
// bucket_csr writes row_ptr/dinv DIRECTLY (bin base bco[b*nb3] is the global
// prefix; cnt + cnt-scan deleted), and build_ew is bin-parallel/coalesced
// (LDS row_ptr slice + binary-search owner lookup; consecutive lanes read
// tmp3 / write ew on 64B lines — was 64-way-scattered 4B packets).
// 4B edge payload src(17b)|ws15. Features bf16-pair packed.

typedef unsigned int u32;
using bfrag = __attribute__((ext_vector_type(8))) short;   // 8 bf16 (4 VGPRs)
using f4    = __attribute__((ext_vector_type(4))) float;   // 4 fp32 acc

__device__ inline u32 pack_bf16(float a, float b) {
    u32 ua = __float_as_uint(a);
    u32 ub = __float_as_uint(b);
    ua += 0x7fffu + ((ua >> 16) & 1u);   // RNE
    ub += 0x7fffu + ((ub >> 16) & 1u);
    return (ua >> 16) | (ub & 0xffff0000u);
}
__device__ inline float bf_lo(u32 v) { return __uint_as_float(v << 16); }
__device__ inline float bf_hi(u32 v) { return __uint_as_float(v & 0xffff0000u); }

// w in [2^-8, 1] -> 15 bits: ws = (bits(w) + rnd - 0x3B800000) >> 12.
__device__ inline u32 pack_w(float w) {
    u32 b = __float_as_uint(w) + 0x800u;       // round mantissa at 11 bits
    if (b < 0x3B800000u) b = 0x3B800000u;      // clamp to 2^-8 (unreachable)
    if (b > 0x3F800000u) b = 0x3F800000u;      // clamp to 1.0
    return (b - 0x3B800000u) >> 12;            // 15 bits
}
__device__ inline float dec_w(u32 e) {
    return __uint_as_float(((e & 0x7fffu) << 12) + 0x3B800000u);
}

__device__ inline bfrag as_bfrag(uint4 v) {
    union { uint4 u; bfrag b; } x; x.u = v; return x.b;
}

__device__ inline void prep_w_chunk(int idx, const float* __restrict__ W1,
                                    const float* __restrict__ W2,
                                    u32* __restrict__ W1t, u32* __restrict__ W2t) {
    if (idx < 128 * 64) {
        int nr = idx >> 6, kd = idx & 63;
        W1t[idx] = pack_bf16(W1[(2 * kd) * 128 + nr], W1[(2 * kd + 1) * 128 + nr]);
    } else if (idx < 128 * 64 + 64 * 64) {
        int i = idx - 128 * 64;
        int nr = i >> 6, kd = i & 63;
        W2t[i] = pack_bf16(W2[(2 * kd) * 64 + nr], W2[(2 * kd + 1) * 64 + nr]);
    }
}

// ---------------- atomic-free CSR build (6 launches) ----------------

// Per-block LDS histogram over coarse bins (dst>>8) -> bc[bin][block].
// Blocks >= nb3 run prep_w; block 0 writes bc[M] = E.
__global__ __launch_bounds__(256) void count_bins_pw(const int* __restrict__ dst,
                                                     int* __restrict__ bc,
                                                     int E, int nbin, int nb3, int M,
                                                     const float* __restrict__ W1,
                                                     const float* __restrict__ W2,
                                                     u32* __restrict__ W1t,
                                                     u32* __restrict__ W2t) {
    __shared__ int hist[512];
    if (blockIdx.x >= (unsigned)nb3) {
        prep_w_chunk((blockIdx.x - nb3) * 256 + threadIdx.x, W1, W2, W1t, W2t);
        return;
    }
    if (blockIdx.x == 0 && threadIdx.x == 0) bc[M] = E;
    for (int t = threadIdx.x; t < nbin; t += 256) hist[t] = 0;
    __syncthreads();
    const int base = blockIdx.x * 2048 + threadIdx.x;
#pragma unroll
    for (int k = 0; k < 8; ++k) {
        int e = base + k * 256;
        if (e < E) atomicAdd(&hist[dst[e] >> 8], 1);
    }
    __syncthreads();
    for (int t = threadIdx.x; t < nbin; t += 256)
        bc[(size_t)t * nb3 + blockIdx.x] = hist[t];
}

// M-scan phase 1: per-1024-chunk sums.
__global__ __launch_bounds__(1024) void scan_reduce_g(const int* __restrict__ a,
                                                      int* __restrict__ bsum, int M) {
    __shared__ int wsum[16];
    int i = blockIdx.x * 1024 + threadIdx.x;
    int v = (i < M) ? a[i] : 0;
#pragma unroll
    for (int off = 32; off > 0; off >>= 1) v += __shfl_down(v, off);
    const int lane = threadIdx.x & 63;
    const int wid  = threadIdx.x >> 6;
    if (lane == 0) wsum[wid] = v;
    __syncthreads();
    if (threadIdx.x < 16) {
        int s = wsum[threadIdx.x];
#pragma unroll
        for (int off = 8; off > 0; off >>= 1) s += __shfl_down(s, off);
        if (threadIdx.x == 0) bsum[blockIdx.x] = s;
    }
}

// M-scan phase 2: in-place exclusive prefix, block offset self-computed.
__global__ __launch_bounds__(1024) void scan_apply_g2(int* __restrict__ a,
                                                      const int* __restrict__ bsum,
                                                      int nb, int M) {
    __shared__ int wsum[16];
    __shared__ int base_s;
    const int lane = threadIdx.x & 63;
    const int wid  = threadIdx.x >> 6;
    int pv = 0;
    for (int t = threadIdx.x; t < (int)blockIdx.x; t += 1024) pv += bsum[t];
#pragma unroll
    for (int off = 32; off > 0; off >>= 1) pv += __shfl_down(pv, off);
    if (lane == 0) wsum[wid] = pv;
    __syncthreads();
    if (threadIdx.x == 0) {
        int s = 0;
#pragma unroll
        for (int w = 0; w < 16; ++w) s += wsum[w];
        base_s = s;
    }
    __syncthreads();
    const int boff = base_s;
    int i = blockIdx.x * 1024 + threadIdx.x;
    int v = (i < M) ? a[i] : 0;
    int x = v;
#pragma unroll
    for (int off = 1; off < 64; off <<= 1) {
        int t = __shfl_up(x, off);
        if (lane >= off) x += t;
    }
    if (lane == 63) wsum[wid] = x;
    __syncthreads();
    if (wid == 0 && lane < 16) {
        int w = wsum[lane];
#pragma unroll
        for (int off = 1; off < 16; off <<= 1) {
            int t = __shfl_up(w, off);
            if (lane >= off) w += t;
        }
        wsum[lane] = w;
    }
    __syncthreads();
    int wave_excl = (wid == 0) ? 0 : wsum[wid - 1];
    if (i < M) a[i] = boff + wave_excl + (x - v);
}

// Scatter edges into per-(bin,block) reserved ranges via LDS cursors.
// Record: (dst&255)<<17 | src  (25 bits).
__global__ __launch_bounds__(256) void scatter_bins(const int* __restrict__ src,
                                                    const int* __restrict__ dst,
                                                    const int* __restrict__ offs,
                                                    u32* __restrict__ tmp,
                                                    int E, int nbin, int nb3) {
    __shared__ int cur[512];
    for (int t = threadIdx.x; t < nbin; t += 256)
        cur[t] = offs[(size_t)t * nb3 + blockIdx.x];
    __syncthreads();
    const int base = blockIdx.x * 2048 + threadIdx.x;
#pragma unroll
    for (int k = 0; k < 8; ++k) {
        int e = base + k * 256;
        if (e < E) {
            int d = dst[e];
            int pos = atomicAdd(&cur[d >> 8], 1);
            tmp[pos] = ((u32)(d & 255) << 17) | (u32)src[e];
        }
    }
}

// One block per bin: LDS 256-way hist + scan. Writes row_ptr/dinv DIRECTLY
// (bin base offs[b*nb3] is the global edge prefix at node b*256) and
// scatters src into fully-dst-sorted tmp3. cnt + cnt-scan eliminated.
__global__ __launch_bounds__(256) void bucket_csr2(const u32* __restrict__ tmp,
                                                   const int* __restrict__ offs,
                                                   u32* __restrict__ tmp3,
                                                   int* __restrict__ row_ptr,
                                                   float* __restrict__ dinv,
                                                   int n, int nb3, int E) {
    __shared__ int hist[256];
    __shared__ int cur[256];
    __shared__ int wtot[4];
    const int b   = blockIdx.x;
    const int beg = offs[(size_t)b * nb3];
    const int end = offs[(size_t)(b + 1) * nb3];   // offs[M] = E for last bin
    hist[threadIdx.x] = 0;
    __syncthreads();
    for (int i = beg + threadIdx.x; i < end; i += 256)
        atomicAdd(&hist[tmp[i] >> 17], 1);
    __syncthreads();
    const int lane = threadIdx.x & 63;
    const int wid  = threadIdx.x >> 6;
    int v = hist[threadIdx.x];
    int x = v;
#pragma unroll
    for (int off = 1; off < 64; off <<= 1) {
        int t = __shfl_up(x, off);
        if (lane >= off) x += t;
    }
    if (lane == 63) wtot[wid] = x;
    __syncthreads();
    int wbase = 0;
    for (int w = 0; w < wid; ++w) wbase += wtot[w];
    const int rp = beg + wbase + x - v;
    cur[threadIdx.x] = rp;
    const int d = b * 256 + threadIdx.x;
    if (d < n) {
        row_ptr[d] = rp;
        dinv[d]    = rsqrtf((float)v + 1.0f);
    }
    if (b == 0 && threadIdx.x == 0) row_ptr[n] = E;
    __syncthreads();
    for (int i = beg + threadIdx.x; i < end; i += 256) {
        u32 r = tmp[i];
        int pos = atomicAdd(&cur[r >> 17], 1);
        tmp3[pos] = r & 0x1ffffu;   // src
    }
}

// Bin-parallel coalesced ew build: block per bin, row_ptr slice + bin dinv
// in LDS, owner node via 8-step binary search. Consecutive lanes read
// consecutive tmp3 and write consecutive ew (64B lines). dinv[src] random
// 4B reads hit L2 (400KB array).
__global__ __launch_bounds__(256) void build_ew2(const u32* __restrict__ tmp3,
                                                 const int* __restrict__ row_ptr,
                                                 const float* __restrict__ dinv,
                                                 u32* __restrict__ ew, int n) {
    __shared__ int   sh_rp[257];
    __shared__ float sh_di[256];
    const int b = blockIdx.x;
    const int t = threadIdx.x;
    const int base = b * 256;
    const int idx  = base + t;
    sh_rp[t] = row_ptr[(idx <= n) ? idx : n];   // pads read row_ptr[n]=E
    if (t == 0) {
        int last = base + 256;
        sh_rp[256] = row_ptr[(last <= n) ? last : n];
    }
    sh_di[t] = (idx < n) ? dinv[idx] : 0.0f;
    __syncthreads();
    const int beg = sh_rp[0];
    const int end = sh_rp[256];
    for (int i = beg + t; i < end; i += 256) {
        u32 s = tmp3[i];
        int lo = 0, hi = 255;
#pragma unroll
        for (int st = 0; st < 8; ++st) {
            int mid = (lo + hi + 1) >> 1;
            if (sh_rp[mid] <= i) lo = mid; else hi = mid - 1;
        }
        ew[i] = (s << 15) | pack_w(dinv[s] * sh_di[lo]);
    }
}

// ---------------- GEMM ----------------

// C[n][OUT] bf16-packed = A[n][128] @ W[128][OUT], via 16x16x32 bf16 MFMA.
// No LDS. Wave handles 32 rows (2 m-frags). Operand swap: mfma(w_frag, a_frag)
// -> D tile = C^T layout: C-row = lane&15, C-col = nt*16 + quad*4 + reg, so
// each lane holds 4 consecutive C-cols -> one uint2 store per tile.
// ABF: A is bf16-pair packed [n][64] dwords; else fp32 [n][128].
template <int OUT, bool ABF>
__global__ __launch_bounds__(256) void gemm_mfma(const void* __restrict__ Ap,
                                                 const u32* __restrict__ Wt,
                                                 u32* __restrict__ C, int n) {
    constexpr int NT = OUT / 16;
    const int lane = threadIdx.x & 63;
    const int wv   = threadIdx.x >> 6;
    const int r15  = lane & 15;
    const int quad = lane >> 4;
    const int rowbase = blockIdx.x * 128 + wv * 32;

    bfrag af[2][4];
#pragma unroll
    for (int mi = 0; mi < 2; ++mi) {
        int row = rowbase + mi * 16 + r15;
        row = (row < n) ? row : (n - 1);
        if constexpr (ABF) {
            const u32* ar = (const u32*)Ap + (size_t)row * 64 + quad * 4;
#pragma unroll
            for (int ks = 0; ks < 4; ++ks)
                af[mi][ks] = as_bfrag(*(const uint4*)(ar + ks * 16));
        } else {
            const float* arf = (const float*)Ap + (size_t)row * 128 + quad * 8;
#pragma unroll
            for (int ks = 0; ks < 4; ++ks) {
                float4 v0 = *(const float4*)(arf + ks * 32);
                float4 v1 = *(const float4*)(arf + ks * 32 + 4);
                uint4 p;
                p.x = pack_bf16(v0.x, v0.y);
                p.y = pack_bf16(v0.z, v0.w);
                p.z = pack_bf16(v1.x, v1.y);
                p.w = pack_bf16(v1.z, v1.w);
                af[mi][ks] = as_bfrag(p);
            }
        }
    }

    f4 acc[2][NT];
#pragma unroll
    for (int mi = 0; mi < 2; ++mi)
#pragma unroll
        for (int nt = 0; nt < NT; ++nt) acc[mi][nt] = (f4)0.0f;

#pragma unroll
    for (int nt = 0; nt < NT; ++nt) {
        const u32* wr = Wt + (size_t)(nt * 16 + r15) * 64 + quad * 4;
#pragma unroll
        for (int ks = 0; ks < 4; ++ks) {
            bfrag bf = as_bfrag(*(const uint4*)(wr + ks * 16));
            acc[0][nt] = __builtin_amdgcn_mfma_f32_16x16x32_bf16(bf, af[0][ks], acc[0][nt], 0, 0, 0);
            acc[1][nt] = __builtin_amdgcn_mfma_f32_16x16x32_bf16(bf, af[1][ks], acc[1][nt], 0, 0, 0);
        }
    }

#pragma unroll
    for (int mi = 0; mi < 2; ++mi) {
        int row = rowbase + mi * 16 + r15;
        if (row < n) {
            u32* cp = C + (size_t)row * (OUT / 2);
#pragma unroll
            for (int nt = 0; nt < NT; ++nt) {
                uint2 p;
                p.x = pack_bf16(acc[mi][nt][0], acc[mi][nt][1]);
                p.y = pack_bf16(acc[mi][nt][2], acc[mi][nt][3]);
                *(uint2*)(cp + nt * 8 + quad * 2) = p;
            }
        }
    }
}

// ---------------- gathers: scalar edge fetch (R10 structure) ----------------

__global__ __launch_bounds__(256) void gather128(const u32* __restrict__ h,
                                                 const float* __restrict__ dinv,
                                                 const int* __restrict__ row_ptr,
                                                 const u32* __restrict__ ew,
                                                 const float* __restrict__ bias,
                                                 u32* __restrict__ outp, int n) {
    const int lane = threadIdx.x & 63;
    int node = blockIdx.x * 4 + (threadIdx.x >> 6);
    if (node >= n) return;
    node = __builtin_amdgcn_readfirstlane(node);

    const float dd  = dinv[node];
    const int   beg = __builtin_amdgcn_readfirstlane(row_ptr[node]);
    const int   end = __builtin_amdgcn_readfirstlane(row_ptr[node + 1]);

    u32 sv = h[(size_t)node * 64 + lane];
    float2 b = ((const float2*)bias)[lane];
    float acc0 = fmaf(bf_lo(sv) * dd, dd, b.x);
    float acc1 = fmaf(bf_hi(sv) * dd, dd, b.y);

    int j = beg;
    for (; j + 16 <= end; j += 16) {
        u32 ep[16];
#pragma unroll
        for (int k = 0; k < 16; ++k) ep[k] = ew[j + k];        // s_load (merged)
        u32 v[16];
#pragma unroll
        for (int k = 0; k < 16; ++k)
            v[k] = h[((size_t)(ep[k] >> 15) << 6) + lane];     // saddr + lane
#pragma unroll
        for (int k = 0; k < 16; ++k) {
            float wf = dec_w(ep[k]);                           // SALU decode
            acc0 = fmaf(wf, bf_lo(v[k]), acc0);
            acc1 = fmaf(wf, bf_hi(v[k]), acc1);
        }
    }
    for (; j < end; j += 8) {
        const int cnt = end - j;                               // 1..15 (SGPR)
        u32 ep[8];
#pragma unroll
        for (int k = 0; k < 8; ++k) {
            int c = j + k;
            ep[k] = ew[(c < end) ? c : end - 1];               // scalar clamp
        }
        u32 v[8];
#pragma unroll
        for (int k = 0; k < 8; ++k)
            v[k] = h[((size_t)(ep[k] >> 15) << 6) + lane];     // pads: L1-hot row
#pragma unroll
        for (int k = 0; k < 8; ++k) {
            float wf = (k < cnt) ? dec_w(ep[k]) : 0.0f;        // scalar select
            acc0 = fmaf(wf, bf_lo(v[k]), acc0);
            acc1 = fmaf(wf, bf_hi(v[k]), acc1);
        }
    }

    // relu + bf16 pack (relu commutes with RNE quantization)
    outp[(size_t)node * 64 + lane] = pack_bf16(fmaxf(acc0, 0.0f), fmaxf(acc1, 0.0f));
}

__global__ __launch_bounds__(256) void gather64(const u32* __restrict__ h,
                                                const float* __restrict__ dinv,
                                                const int* __restrict__ row_ptr,
                                                const u32* __restrict__ ew,
                                                const float* __restrict__ bias,
                                                float* __restrict__ outp, int n) {
    const int lane   = threadIdx.x & 63;
    const int lane32 = lane & 31;
    const int sub    = lane >> 5;
    int node = blockIdx.x * 4 + (threadIdx.x >> 6);
    if (node >= n) return;
    node = __builtin_amdgcn_readfirstlane(node);

    const int beg = __builtin_amdgcn_readfirstlane(row_ptr[node]);
    const int end = __builtin_amdgcn_readfirstlane(row_ptr[node + 1]);

    float acc0 = 0.0f, acc1 = 0.0f;
    if (sub == 0) {
        const float dd = dinv[node];
        u32 sv = h[(size_t)node * 32 + lane32];
        float2 b = ((const float2*)bias)[lane32];
        acc0 = fmaf(bf_lo(sv) * dd, dd, b.x);
        acc1 = fmaf(bf_hi(sv) * dd, dd, b.y);
    }

    int j = beg;
    for (; j + 16 <= end; j += 16) {
        u32 ep[16];
#pragma unroll
        for (int k = 0; k < 16; ++k) ep[k] = ew[j + k];        // s_load (merged)
        u32 v[8]; float wl[8];
#pragma unroll
        for (int p = 0; p < 8; ++p) {
            u32 e0 = ep[2 * p], e1 = ep[2 * p + 1];
            u32 so = sub ? (e1 >> 15) : (e0 >> 15);            // cndmask
            wl[p]  = sub ? dec_w(e1) : dec_w(e0);              // cndmask
            v[p]   = h[((size_t)so << 5) + lane32];
        }
#pragma unroll
        for (int p = 0; p < 8; ++p) {
            acc0 = fmaf(wl[p], bf_lo(v[p]), acc0);
            acc1 = fmaf(wl[p], bf_hi(v[p]), acc1);
        }
    }
    for (; j < end; j += 8) {
        const int cnt = end - j;                               // 1..15 (SGPR)
        u32 ep[8];
#pragma unroll
        for (int k = 0; k < 8; ++k) {
            int c = j + k;
            ep[k] = ew[(c < end) ? c : end - 1];               // scalar clamp
        }
        u32 v[4]; float wl[4];
#pragma unroll
        for (int p = 0; p < 4; ++p) {
            u32 e0 = ep[2 * p], e1 = ep[2 * p + 1];
            float w0 = (2 * p     < cnt) ? dec_w(e0) : 0.0f;   // scalar select
            float w1 = (2 * p + 1 < cnt) ? dec_w(e1) : 0.0f;
            u32 so = sub ? (e1 >> 15) : (e0 >> 15);
            wl[p]  = sub ? w1 : w0;
            v[p]   = h[((size_t)so << 5) + lane32];            // pads: L1-hot row
        }
#pragma unroll
        for (int p = 0; p < 4; ++p) {
            acc0 = fmaf(wl[p], bf_lo(v[p]), acc0);
            acc1 = fmaf(wl[p], bf_hi(v[p]), acc1);
        }
    }

    acc0 += __shfl_xor(acc0, 32);
    acc1 += __shfl_xor(acc1, 32);
    if (sub == 0)
        ((float2*)(outp + (size_t)node * 64))[lane32] = make_float2(acc0, acc1);
}

extern "C" void kernel_launch(void* const* d_in, const int* in_sizes, int n_in,
                              void* d_out, int out_size, void* d_ws, size_t ws_size,
                              hipStream_t stream) {
    const float* x  = (const float*)d_in[0];
    const int*   ei = (const int*)d_in[1];
    const float* W1 = (const float*)d_in[2];
    const float* b1 = (const float*)d_in[3];
    const float* W2 = (const float*)d_in[4];
    const float* b2 = (const float*)d_in[5];
    float*       out = (float*)d_out;

    const int n = in_sizes[0] / 128;   // 100000
    const int E = in_sizes[1] / 2;     // 1600000
    const int* srcv = ei;
    const int* dstv = ei + E;

    const int NP = 102400;
    u32* wsd = (u32*)d_ws;
    float* dinv    = (float*)wsd;                        // NP
    int*   row_ptr = (int*)(wsd + NP);                   // NP
    u32*   ew      = wsd + 2 * (size_t)NP;               // E
    u32*   h1u     = ew + E;                             // n*64 (gemm1 C / gather128 in)
    u32*   agg1b   = h1u + (size_t)n * 64;               // n*64 (gather128 out / gemm2 A)
    u32*   W1t     = agg1b + (size_t)n * 64;             // 8192
    u32*   W2t     = W1t + 8192;                         // 4096
    u32*   h2u     = h1u;                                // gemm2 C: n*32, reuses h1u

    // CSR scratch — overlaid on h1u (dead until gemm1 writes it):
    int*   bco  = (int*)(h1u + 131072);                  // M+1
    u32*   tmp2 = h1u + 524288;                          // E
    u32*   tmp3 = tmp2 + (size_t)E;                      // E
    int*   bsum = (int*)(h1u + 4000000);                 // 512

    const int NBIN = (n + 255) >> 8;          // 391
    const int NB3  = (E + 2047) / 2048;       // 782
    const int M    = NBIN * NB3;              // 305,762
    const int MB   = (M + 1023) / 1024;       // 299

    // --- CSR build (no global atomics; 6 launches) ---
    count_bins_pw<<<NB3 + 48, 256, 0, stream>>>(dstv, bco, E, NBIN, NB3, M,
                                                W1, W2, W1t, W2t);
    scan_reduce_g<<<MB, 1024, 0, stream>>>(bco, bsum, M);
    scan_apply_g2<<<MB, 1024, 0, stream>>>(bco, bsum, MB, M);
    scatter_bins<<<NB3, 256, 0, stream>>>(srcv, dstv, bco, tmp2, E, NBIN, NB3);
    bucket_csr2<<<NBIN, 256, 0, stream>>>(tmp2, bco, tmp3, row_ptr, dinv, n, NB3, E);
    build_ew2<<<NBIN, 256, 0, stream>>>(tmp3, row_ptr, dinv, ew, n);

    const int gblocks = (n + 127) / 128;  // 782
    // --- layer 1 ---
    gemm_mfma<128, false><<<gblocks, 256, 0, stream>>>(x, W1t, h1u, n);
    gather128<<<(n + 3) / 4, 256, 0, stream>>>(h1u, dinv, row_ptr, ew, b1, agg1b, n);

    // --- layer 2 ---
    gemm_mfma<64, true><<<gblocks, 256, 0, stream>>>(agg1b, W2t, h2u, n);
    gather64<<<(n + 3) / 4, 256, 0, stream>>>(h2u, dinv, row_ptr, ew, b2, out, n);
}

// Round 9
// 290.127 us; speedup vs baseline: 3.7626x; 1.0136x over previous
//
#include <hip/hip_runtime.h>

// GCN 2-layer. R6: bf16-MFMA GEMMs (no LDS, operand-swap epilogue). R9:
// atomic-free CSR (two-level bucket sort; device fetch-add ~24 Gops/s wall).
// R10: scalar edge fetch in gathers. R11 (reverted): slab slicing. R13
// (reverted): cooperative CSR (grid.sync ~800us). R14: bucket emits
// row_ptr/dinv directly; coalesced build_ew. R15: tmp3+build_ew DELETED —
// bucket split into bucket_hist (hist+scan -> row_ptr/dinv) and bucket_ew
// (cursor reload from row_ptr, scatter straight into ew with inline
// pack_w(dinv[src]*dinv[dst]); dinv valid across the launch boundary);
// bucket_ew FUSED with gemm1 (independent work — CSR scratch moved to the
// agg1b overlay so gemm1's h1u write is disjoint). 10 -> 9 launches.
// 4B edge payload src(17b)|ws15. Features bf16-pair packed.

typedef unsigned int u32;
using bfrag = __attribute__((ext_vector_type(8))) short;   // 8 bf16 (4 VGPRs)
using f4    = __attribute__((ext_vector_type(4))) float;   // 4 fp32 acc

__device__ inline u32 pack_bf16(float a, float b) {
    u32 ua = __float_as_uint(a);
    u32 ub = __float_as_uint(b);
    ua += 0x7fffu + ((ua >> 16) & 1u);   // RNE
    ub += 0x7fffu + ((ub >> 16) & 1u);
    return (ua >> 16) | (ub & 0xffff0000u);
}
__device__ inline float bf_lo(u32 v) { return __uint_as_float(v << 16); }
__device__ inline float bf_hi(u32 v) { return __uint_as_float(v & 0xffff0000u); }

// w in [2^-8, 1] -> 15 bits: ws = (bits(w) + rnd - 0x3B800000) >> 12.
__device__ inline u32 pack_w(float w) {
    u32 b = __float_as_uint(w) + 0x800u;       // round mantissa at 11 bits
    if (b < 0x3B800000u) b = 0x3B800000u;      // clamp to 2^-8 (unreachable)
    if (b > 0x3F800000u) b = 0x3F800000u;      // clamp to 1.0
    return (b - 0x3B800000u) >> 12;            // 15 bits
}
__device__ inline float dec_w(u32 e) {
    return __uint_as_float(((e & 0x7fffu) << 12) + 0x3B800000u);
}

__device__ inline bfrag as_bfrag(uint4 v) {
    union { uint4 u; bfrag b; } x; x.u = v; return x.b;
}

__device__ inline void prep_w_chunk(int idx, const float* __restrict__ W1,
                                    const float* __restrict__ W2,
                                    u32* __restrict__ W1t, u32* __restrict__ W2t) {
    if (idx < 128 * 64) {
        int nr = idx >> 6, kd = idx & 63;
        W1t[idx] = pack_bf16(W1[(2 * kd) * 128 + nr], W1[(2 * kd + 1) * 128 + nr]);
    } else if (idx < 128 * 64 + 64 * 64) {
        int i = idx - 128 * 64;
        int nr = i >> 6, kd = i & 63;
        W2t[i] = pack_bf16(W2[(2 * kd) * 64 + nr], W2[(2 * kd + 1) * 64 + nr]);
    }
}

// ---------------- GEMM body (shared by gemm2 kernel + fused gemm1) --------

// C[n][OUT] bf16-packed = A[n][128] @ W[128][OUT], via 16x16x32 bf16 MFMA.
// Operand swap: mfma(w_frag, a_frag) -> lane holds 4 consecutive C-cols.
// ABF: A bf16-pair packed [n][64] dwords; else fp32 [n][128].
template <int OUT, bool ABF>
__device__ inline void gemm_body(int bid, const void* __restrict__ Ap,
                                 const u32* __restrict__ Wt,
                                 u32* __restrict__ C, int n) {
    constexpr int NT = OUT / 16;
    const int lane = threadIdx.x & 63;
    const int wv   = threadIdx.x >> 6;
    const int r15  = lane & 15;
    const int quad = lane >> 4;
    const int rowbase = bid * 128 + wv * 32;

    bfrag af[2][4];
#pragma unroll
    for (int mi = 0; mi < 2; ++mi) {
        int row = rowbase + mi * 16 + r15;
        row = (row < n) ? row : (n - 1);
        if constexpr (ABF) {
            const u32* ar = (const u32*)Ap + (size_t)row * 64 + quad * 4;
#pragma unroll
            for (int ks = 0; ks < 4; ++ks)
                af[mi][ks] = as_bfrag(*(const uint4*)(ar + ks * 16));
        } else {
            const float* arf = (const float*)Ap + (size_t)row * 128 + quad * 8;
#pragma unroll
            for (int ks = 0; ks < 4; ++ks) {
                float4 v0 = *(const float4*)(arf + ks * 32);
                float4 v1 = *(const float4*)(arf + ks * 32 + 4);
                uint4 p;
                p.x = pack_bf16(v0.x, v0.y);
                p.y = pack_bf16(v0.z, v0.w);
                p.z = pack_bf16(v1.x, v1.y);
                p.w = pack_bf16(v1.z, v1.w);
                af[mi][ks] = as_bfrag(p);
            }
        }
    }

    f4 acc[2][NT];
#pragma unroll
    for (int mi = 0; mi < 2; ++mi)
#pragma unroll
        for (int nt = 0; nt < NT; ++nt) acc[mi][nt] = (f4)0.0f;

#pragma unroll
    for (int nt = 0; nt < NT; ++nt) {
        const u32* wr = Wt + (size_t)(nt * 16 + r15) * 64 + quad * 4;
#pragma unroll
        for (int ks = 0; ks < 4; ++ks) {
            bfrag bf = as_bfrag(*(const uint4*)(wr + ks * 16));
            acc[0][nt] = __builtin_amdgcn_mfma_f32_16x16x32_bf16(bf, af[0][ks], acc[0][nt], 0, 0, 0);
            acc[1][nt] = __builtin_amdgcn_mfma_f32_16x16x32_bf16(bf, af[1][ks], acc[1][nt], 0, 0, 0);
        }
    }

#pragma unroll
    for (int mi = 0; mi < 2; ++mi) {
        int row = rowbase + mi * 16 + r15;
        if (row < n) {
            u32* cp = C + (size_t)row * (OUT / 2);
#pragma unroll
            for (int nt = 0; nt < NT; ++nt) {
                uint2 p;
                p.x = pack_bf16(acc[mi][nt][0], acc[mi][nt][1]);
                p.y = pack_bf16(acc[mi][nt][2], acc[mi][nt][3]);
                *(uint2*)(cp + nt * 8 + quad * 2) = p;
            }
        }
    }
}

// ---------------- atomic-free CSR build ----------------

// Per-block LDS histogram over coarse bins (dst>>8) -> bc[bin][block].
// Blocks >= nb3 run prep_w; block 0 writes bc[M] = E.
__global__ __launch_bounds__(256) void count_bins_pw(const int* __restrict__ dst,
                                                     int* __restrict__ bc,
                                                     int E, int nbin, int nb3, int M,
                                                     const float* __restrict__ W1,
                                                     const float* __restrict__ W2,
                                                     u32* __restrict__ W1t,
                                                     u32* __restrict__ W2t) {
    __shared__ int hist[512];
    if (blockIdx.x >= (unsigned)nb3) {
        prep_w_chunk((blockIdx.x - nb3) * 256 + threadIdx.x, W1, W2, W1t, W2t);
        return;
    }
    if (blockIdx.x == 0 && threadIdx.x == 0) bc[M] = E;
    for (int t = threadIdx.x; t < nbin; t += 256) hist[t] = 0;
    __syncthreads();
    const int base = blockIdx.x * 2048 + threadIdx.x;
#pragma unroll
    for (int k = 0; k < 8; ++k) {
        int e = base + k * 256;
        if (e < E) atomicAdd(&hist[dst[e] >> 8], 1);
    }
    __syncthreads();
    for (int t = threadIdx.x; t < nbin; t += 256)
        bc[(size_t)t * nb3 + blockIdx.x] = hist[t];
}

// M-scan phase 1: per-1024-chunk sums.
__global__ __launch_bounds__(1024) void scan_reduce_g(const int* __restrict__ a,
                                                      int* __restrict__ bsum, int M) {
    __shared__ int wsum[16];
    int i = blockIdx.x * 1024 + threadIdx.x;
    int v = (i < M) ? a[i] : 0;
#pragma unroll
    for (int off = 32; off > 0; off >>= 1) v += __shfl_down(v, off);
    const int lane = threadIdx.x & 63;
    const int wid  = threadIdx.x >> 6;
    if (lane == 0) wsum[wid] = v;
    __syncthreads();
    if (threadIdx.x < 16) {
        int s = wsum[threadIdx.x];
#pragma unroll
        for (int off = 8; off > 0; off >>= 1) s += __shfl_down(s, off);
        if (threadIdx.x == 0) bsum[blockIdx.x] = s;
    }
}

// M-scan phase 2: in-place exclusive prefix, block offset self-computed.
__global__ __launch_bounds__(1024) void scan_apply_g2(int* __restrict__ a,
                                                      const int* __restrict__ bsum,
                                                      int nb, int M) {
    __shared__ int wsum[16];
    __shared__ int base_s;
    const int lane = threadIdx.x & 63;
    const int wid  = threadIdx.x >> 6;
    int pv = 0;
    for (int t = threadIdx.x; t < (int)blockIdx.x; t += 1024) pv += bsum[t];
#pragma unroll
    for (int off = 32; off > 0; off >>= 1) pv += __shfl_down(pv, off);
    if (lane == 0) wsum[wid] = pv;
    __syncthreads();
    if (threadIdx.x == 0) {
        int s = 0;
#pragma unroll
        for (int w = 0; w < 16; ++w) s += wsum[w];
        base_s = s;
    }
    __syncthreads();
    const int boff = base_s;
    int i = blockIdx.x * 1024 + threadIdx.x;
    int v = (i < M) ? a[i] : 0;
    int x = v;
#pragma unroll
    for (int off = 1; off < 64; off <<= 1) {
        int t = __shfl_up(x, off);
        if (lane >= off) x += t;
    }
    if (lane == 63) wsum[wid] = x;
    __syncthreads();
    if (wid == 0 && lane < 16) {
        int w = wsum[lane];
#pragma unroll
        for (int off = 1; off < 16; off <<= 1) {
            int t = __shfl_up(w, off);
            if (lane >= off) w += t;
        }
        wsum[lane] = w;
    }
    __syncthreads();
    int wave_excl = (wid == 0) ? 0 : wsum[wid - 1];
    if (i < M) a[i] = boff + wave_excl + (x - v);
}

// Scatter edges into per-(bin,block) reserved ranges via LDS cursors.
// Record: (dst&255)<<17 | src  (25 bits).
__global__ __launch_bounds__(256) void scatter_bins(const int* __restrict__ src,
                                                    const int* __restrict__ dst,
                                                    const int* __restrict__ offs,
                                                    u32* __restrict__ tmp,
                                                    int E, int nbin, int nb3) {
    __shared__ int cur[512];
    for (int t = threadIdx.x; t < nbin; t += 256)
        cur[t] = offs[(size_t)t * nb3 + blockIdx.x];
    __syncthreads();
    const int base = blockIdx.x * 2048 + threadIdx.x;
#pragma unroll
    for (int k = 0; k < 8; ++k) {
        int e = base + k * 256;
        if (e < E) {
            int d = dst[e];
            int pos = atomicAdd(&cur[d >> 8], 1);
            tmp[pos] = ((u32)(d & 255) << 17) | (u32)src[e];
        }
    }
}

// One block per bin: LDS 256-way hist + scan -> row_ptr/dinv directly
// (bin base offs[b*nb3] is the global edge prefix at node b*256).
__global__ __launch_bounds__(256) void bucket_hist(const u32* __restrict__ tmp,
                                                   const int* __restrict__ offs,
                                                   int* __restrict__ row_ptr,
                                                   float* __restrict__ dinv,
                                                   int n, int nb3, int E) {
    __shared__ int hist[256];
    __shared__ int wtot[4];
    const int b   = blockIdx.x;
    const int beg = offs[(size_t)b * nb3];
    const int end = offs[(size_t)(b + 1) * nb3];   // offs[M] = E for last bin
    hist[threadIdx.x] = 0;
    __syncthreads();
    for (int i = beg + threadIdx.x; i < end; i += 256)
        atomicAdd(&hist[tmp[i] >> 17], 1);
    __syncthreads();
    const int lane = threadIdx.x & 63;
    const int wid  = threadIdx.x >> 6;
    int v = hist[threadIdx.x];
    int x = v;
#pragma unroll
    for (int off = 1; off < 64; off <<= 1) {
        int t = __shfl_up(x, off);
        if (lane >= off) x += t;
    }
    if (lane == 63) wtot[wid] = x;
    __syncthreads();
    int wbase = 0;
    for (int w = 0; w < wid; ++w) wbase += wtot[w];
    const int rp = beg + wbase + x - v;
    const int d = b * 256 + threadIdx.x;
    if (d < n) {
        row_ptr[d] = rp;
        dinv[d]    = rsqrtf((float)v + 1.0f);
    }
    if (b == 0 && threadIdx.x == 0) row_ptr[n] = E;
}

// Fused: blocks < nbin scatter tmp2 records straight into ew (cursors from
// row_ptr; dinv fully valid across the launch boundary; dinv[src] random
// reads hit L2 - 400KB array). Blocks >= nbin run gemm1 (independent:
// reads x/W1t, writes h1u - CSR scratch lives on the agg1b overlay).
__global__ __launch_bounds__(256) void bucket_ew_gemm1(
    const u32* __restrict__ tmp, const int* __restrict__ offs,
    const int* __restrict__ row_ptr, const float* __restrict__ dinv,
    u32* __restrict__ ew, int n, int nb3, int nbin,
    const float* __restrict__ x, const u32* __restrict__ W1t,
    u32* __restrict__ h1u) {
    if (blockIdx.x >= (unsigned)nbin) {
        gemm_body<128, false>(blockIdx.x - nbin, x, W1t, h1u, n);
        return;
    }
    __shared__ int   cur[256];
    __shared__ float sdi[256];
    const int b = blockIdx.x;
    const int t = threadIdx.x;
    const int beg = offs[(size_t)b * nb3];
    const int end = offs[(size_t)(b + 1) * nb3];
    const int d = b * 256 + t;
    cur[t] = row_ptr[(d <= n) ? d : n];
    sdi[t] = (d < n) ? dinv[d] : 0.0f;
    __syncthreads();
    for (int i = beg + t; i < end; i += 256) {
        u32 r = tmp[i];
        int k = r >> 17;
        int pos = atomicAdd(&cur[k], 1);
        u32 s = r & 0x1ffffu;
        ew[pos] = (s << 15) | pack_w(dinv[s] * sdi[k]);
    }
}

// ---------------- layer-2 GEMM ----------------

template <int OUT, bool ABF>
__global__ __launch_bounds__(256) void gemm_mfma(const void* __restrict__ Ap,
                                                 const u32* __restrict__ Wt,
                                                 u32* __restrict__ C, int n) {
    gemm_body<OUT, ABF>(blockIdx.x, Ap, Wt, C, n);
}

// ---------------- gathers: scalar edge fetch (R10 structure) ----------------

__global__ __launch_bounds__(256) void gather128(const u32* __restrict__ h,
                                                 const float* __restrict__ dinv,
                                                 const int* __restrict__ row_ptr,
                                                 const u32* __restrict__ ew,
                                                 const float* __restrict__ bias,
                                                 u32* __restrict__ outp, int n) {
    const int lane = threadIdx.x & 63;
    int node = blockIdx.x * 4 + (threadIdx.x >> 6);
    if (node >= n) return;
    node = __builtin_amdgcn_readfirstlane(node);

    const float dd  = dinv[node];
    const int   beg = __builtin_amdgcn_readfirstlane(row_ptr[node]);
    const int   end = __builtin_amdgcn_readfirstlane(row_ptr[node + 1]);

    u32 sv = h[(size_t)node * 64 + lane];
    float2 b = ((const float2*)bias)[lane];
    float acc0 = fmaf(bf_lo(sv) * dd, dd, b.x);
    float acc1 = fmaf(bf_hi(sv) * dd, dd, b.y);

    int j = beg;
    for (; j + 16 <= end; j += 16) {
        u32 ep[16];
#pragma unroll
        for (int k = 0; k < 16; ++k) ep[k] = ew[j + k];        // s_load (merged)
        u32 v[16];
#pragma unroll
        for (int k = 0; k < 16; ++k)
            v[k] = h[((size_t)(ep[k] >> 15) << 6) + lane];     // saddr + lane
#pragma unroll
        for (int k = 0; k < 16; ++k) {
            float wf = dec_w(ep[k]);                           // SALU decode
            acc0 = fmaf(wf, bf_lo(v[k]), acc0);
            acc1 = fmaf(wf, bf_hi(v[k]), acc1);
        }
    }
    for (; j < end; j += 8) {
        const int cnt = end - j;                               // 1..15 (SGPR)
        u32 ep[8];
#pragma unroll
        for (int k = 0; k < 8; ++k) {
            int c = j + k;
            ep[k] = ew[(c < end) ? c : end - 1];               // scalar clamp
        }
        u32 v[8];
#pragma unroll
        for (int k = 0; k < 8; ++k)
            v[k] = h[((size_t)(ep[k] >> 15) << 6) + lane];     // pads: L1-hot row
#pragma unroll
        for (int k = 0; k < 8; ++k) {
            float wf = (k < cnt) ? dec_w(ep[k]) : 0.0f;        // scalar select
            acc0 = fmaf(wf, bf_lo(v[k]), acc0);
            acc1 = fmaf(wf, bf_hi(v[k]), acc1);
        }
    }

    // relu + bf16 pack (relu commutes with RNE quantization)
    outp[(size_t)node * 64 + lane] = pack_bf16(fmaxf(acc0, 0.0f), fmaxf(acc1, 0.0f));
}

__global__ __launch_bounds__(256) void gather64(const u32* __restrict__ h,
                                                const float* __restrict__ dinv,
                                                const int* __restrict__ row_ptr,
                                                const u32* __restrict__ ew,
                                                const float* __restrict__ bias,
                                                float* __restrict__ outp, int n) {
    const int lane   = threadIdx.x & 63;
    const int lane32 = lane & 31;
    const int sub    = lane >> 5;
    int node = blockIdx.x * 4 + (threadIdx.x >> 6);
    if (node >= n) return;
    node = __builtin_amdgcn_readfirstlane(node);

    const int beg = __builtin_amdgcn_readfirstlane(row_ptr[node]);
    const int end = __builtin_amdgcn_readfirstlane(row_ptr[node + 1]);

    float acc0 = 0.0f, acc1 = 0.0f;
    if (sub == 0) {
        const float dd = dinv[node];
        u32 sv = h[(size_t)node * 32 + lane32];
        float2 b = ((const float2*)bias)[lane32];
        acc0 = fmaf(bf_lo(sv) * dd, dd, b.x);
        acc1 = fmaf(bf_hi(sv) * dd, dd, b.y);
    }

    int j = beg;
    for (; j + 16 <= end; j += 16) {
        u32 ep[16];
#pragma unroll
        for (int k = 0; k < 16; ++k) ep[k] = ew[j + k];        // s_load (merged)
        u32 v[8]; float wl[8];
#pragma unroll
        for (int p = 0; p < 8; ++p) {
            u32 e0 = ep[2 * p], e1 = ep[2 * p + 1];
            u32 so = sub ? (e1 >> 15) : (e0 >> 15);            // cndmask
            wl[p]  = sub ? dec_w(e1) : dec_w(e0);              // cndmask
            v[p]   = h[((size_t)so << 5) + lane32];
        }
#pragma unroll
        for (int p = 0; p < 8; ++p) {
            acc0 = fmaf(wl[p], bf_lo(v[p]), acc0);
            acc1 = fmaf(wl[p], bf_hi(v[p]), acc1);
        }
    }
    for (; j < end; j += 8) {
        const int cnt = end - j;                               // 1..15 (SGPR)
        u32 ep[8];
#pragma unroll
        for (int k = 0; k < 8; ++k) {
            int c = j + k;
            ep[k] = ew[(c < end) ? c : end - 1];               // scalar clamp
        }
        u32 v[4]; float wl[4];
#pragma unroll
        for (int p = 0; p < 4; ++p) {
            u32 e0 = ep[2 * p], e1 = ep[2 * p + 1];
            float w0 = (2 * p     < cnt) ? dec_w(e0) : 0.0f;   // scalar select
            float w1 = (2 * p + 1 < cnt) ? dec_w(e1) : 0.0f;
            u32 so = sub ? (e1 >> 15) : (e0 >> 15);
            wl[p]  = sub ? w1 : w0;
            v[p]   = h[((size_t)so << 5) + lane32];            // pads: L1-hot row
        }
#pragma unroll
        for (int p = 0; p < 4; ++p) {
            acc0 = fmaf(wl[p], bf_lo(v[p]), acc0);
            acc1 = fmaf(wl[p], bf_hi(v[p]), acc1);
        }
    }

    acc0 += __shfl_xor(acc0, 32);
    acc1 += __shfl_xor(acc1, 32);
    if (sub == 0)
        ((float2*)(outp + (size_t)node * 64))[lane32] = make_float2(acc0, acc1);
}

extern "C" void kernel_launch(void* const* d_in, const int* in_sizes, int n_in,
                              void* d_out, int out_size, void* d_ws, size_t ws_size,
                              hipStream_t stream) {
    const float* x  = (const float*)d_in[0];
    const int*   ei = (const int*)d_in[1];
    const float* W1 = (const float*)d_in[2];
    const float* b1 = (const float*)d_in[3];
    const float* W2 = (const float*)d_in[4];
    const float* b2 = (const float*)d_in[5];
    float*       out = (float*)d_out;

    const int n = in_sizes[0] / 128;   // 100000
    const int E = in_sizes[1] / 2;     // 1600000
    const int* srcv = ei;
    const int* dstv = ei + E;

    const int NP = 102400;
    u32* wsd = (u32*)d_ws;
    float* dinv    = (float*)wsd;                        // NP
    int*   row_ptr = (int*)(wsd + NP);                   // NP
    u32*   ew      = wsd + 2 * (size_t)NP;               // E
    u32*   h1u     = ew + E;                             // n*64 (gemm1 C / gather128 in)
    u32*   agg1b   = h1u + (size_t)n * 64;               // n*64 (gather128 out / gemm2 A)
    u32*   W1t     = agg1b + (size_t)n * 64;             // 8192
    u32*   W2t     = W1t + 8192;                         // 4096
    u32*   h2u     = h1u;                                // gemm2 C: n*32, reuses h1u

    // CSR scratch — overlaid on agg1b (dead until gather128 writes it),
    // so gemm1 (writes h1u) is independent of the CSR tail -> fusable.
    int*   bco  = (int*)agg1b;                           // M+1 (305,763)
    u32*   tmp2 = agg1b + 400000;                        // E
    int*   bsum = (int*)(agg1b + 2200000);               // 512

    const int NBIN = (n + 255) >> 8;          // 391
    const int NB3  = (E + 2047) / 2048;       // 782
    const int M    = NBIN * NB3;              // 305,762
    const int MB   = (M + 1023) / 1024;       // 299

    const int gblocks = (n + 127) / 128;      // 782

    // --- CSR build (no global atomics) + fused gemm1 ---
    count_bins_pw<<<NB3 + 48, 256, 0, stream>>>(dstv, bco, E, NBIN, NB3, M,
                                                W1, W2, W1t, W2t);
    scan_reduce_g<<<MB, 1024, 0, stream>>>(bco, bsum, M);
    scan_apply_g2<<<MB, 1024, 0, stream>>>(bco, bsum, MB, M);
    scatter_bins<<<NB3, 256, 0, stream>>>(srcv, dstv, bco, tmp2, E, NBIN, NB3);
    bucket_hist<<<NBIN, 256, 0, stream>>>(tmp2, bco, row_ptr, dinv, n, NB3, E);
    bucket_ew_gemm1<<<NBIN + gblocks, 256, 0, stream>>>(tmp2, bco, row_ptr, dinv,
                                                        ew, n, NB3, NBIN,
                                                        x, W1t, h1u);

    // --- layer 1 gather ---
    gather128<<<(n + 3) / 4, 256, 0, stream>>>(h1u, dinv, row_ptr, ew, b1, agg1b, n);

    // --- layer 2 ---
    gemm_mfma<64, true><<<gblocks, 256, 0, stream>>>(agg1b, W2t, h2u, n);
    gather64<<<(n + 3) / 4, 256, 0, stream>>>(h2u, dinv, row_ptr, ew, b2, out, n);
}

// Round 10
// 283.297 us; speedup vs baseline: 3.8533x; 1.0241x over previous
//
#include <hip/hip_runtime.h>

// GCN 2-layer. R6: bf16-MFMA GEMMs (no LDS, operand-swap epilogue). R9:
// atomic-free CSR (two-level bucket sort; device fetch-add ~24 Gops/s wall).
// R10: scalar edge fetch in gathers. R11 (reverted): slab slicing. R13
// (reverted): cooperative CSR. R14: bucket emits row_ptr/dinv directly.
// R15: bucket_ew scatters straight into ew, fused with gemm1. R16:
// gather128 FUSED with gemm2 — agg rows parked in LDS (bit-identical bf16),
// one barrier, per-wave 16-col MFMA tile, direct h2 write. Deletes the
// 25.6MB agg1b write + 25.6MB gemm2 re-read + one launch. h2 lives in the
// old agg1b slot (h1u stays live during the fused kernel).
// 4B edge payload src(17b)|ws15. Features bf16-pair packed.

typedef unsigned int u32;
using bfrag = __attribute__((ext_vector_type(8))) short;   // 8 bf16 (4 VGPRs)
using f4    = __attribute__((ext_vector_type(4))) float;   // 4 fp32 acc

__device__ inline u32 pack_bf16(float a, float b) {
    u32 ua = __float_as_uint(a);
    u32 ub = __float_as_uint(b);
    ua += 0x7fffu + ((ua >> 16) & 1u);   // RNE
    ub += 0x7fffu + ((ub >> 16) & 1u);
    return (ua >> 16) | (ub & 0xffff0000u);
}
__device__ inline float bf_lo(u32 v) { return __uint_as_float(v << 16); }
__device__ inline float bf_hi(u32 v) { return __uint_as_float(v & 0xffff0000u); }

// w in [2^-8, 1] -> 15 bits: ws = (bits(w) + rnd - 0x3B800000) >> 12.
__device__ inline u32 pack_w(float w) {
    u32 b = __float_as_uint(w) + 0x800u;       // round mantissa at 11 bits
    if (b < 0x3B800000u) b = 0x3B800000u;      // clamp to 2^-8 (unreachable)
    if (b > 0x3F800000u) b = 0x3F800000u;      // clamp to 1.0
    return (b - 0x3B800000u) >> 12;            // 15 bits
}
__device__ inline float dec_w(u32 e) {
    return __uint_as_float(((e & 0x7fffu) << 12) + 0x3B800000u);
}

__device__ inline bfrag as_bfrag(uint4 v) {
    union { uint4 u; bfrag b; } x; x.u = v; return x.b;
}

__device__ inline void prep_w_chunk(int idx, const float* __restrict__ W1,
                                    const float* __restrict__ W2,
                                    u32* __restrict__ W1t, u32* __restrict__ W2t) {
    if (idx < 128 * 64) {
        int nr = idx >> 6, kd = idx & 63;
        W1t[idx] = pack_bf16(W1[(2 * kd) * 128 + nr], W1[(2 * kd + 1) * 128 + nr]);
    } else if (idx < 128 * 64 + 64 * 64) {
        int i = idx - 128 * 64;
        int nr = i >> 6, kd = i & 63;
        W2t[i] = pack_bf16(W2[(2 * kd) * 64 + nr], W2[(2 * kd + 1) * 64 + nr]);
    }
}

// ---------------- GEMM body (used by fused gemm1) --------

// C[n][OUT] bf16-packed = A[n][128] @ W[128][OUT], via 16x16x32 bf16 MFMA.
// Operand swap: mfma(w_frag, a_frag) -> lane holds 4 consecutive C-cols.
template <int OUT, bool ABF>
__device__ inline void gemm_body(int bid, const void* __restrict__ Ap,
                                 const u32* __restrict__ Wt,
                                 u32* __restrict__ C, int n) {
    constexpr int NT = OUT / 16;
    const int lane = threadIdx.x & 63;
    const int wv   = threadIdx.x >> 6;
    const int r15  = lane & 15;
    const int quad = lane >> 4;
    const int rowbase = bid * 128 + wv * 32;

    bfrag af[2][4];
#pragma unroll
    for (int mi = 0; mi < 2; ++mi) {
        int row = rowbase + mi * 16 + r15;
        row = (row < n) ? row : (n - 1);
        if constexpr (ABF) {
            const u32* ar = (const u32*)Ap + (size_t)row * 64 + quad * 4;
#pragma unroll
            for (int ks = 0; ks < 4; ++ks)
                af[mi][ks] = as_bfrag(*(const uint4*)(ar + ks * 16));
        } else {
            const float* arf = (const float*)Ap + (size_t)row * 128 + quad * 8;
#pragma unroll
            for (int ks = 0; ks < 4; ++ks) {
                float4 v0 = *(const float4*)(arf + ks * 32);
                float4 v1 = *(const float4*)(arf + ks * 32 + 4);
                uint4 p;
                p.x = pack_bf16(v0.x, v0.y);
                p.y = pack_bf16(v0.z, v0.w);
                p.z = pack_bf16(v1.x, v1.y);
                p.w = pack_bf16(v1.z, v1.w);
                af[mi][ks] = as_bfrag(p);
            }
        }
    }

    f4 acc[2][NT];
#pragma unroll
    for (int mi = 0; mi < 2; ++mi)
#pragma unroll
        for (int nt = 0; nt < NT; ++nt) acc[mi][nt] = (f4)0.0f;

#pragma unroll
    for (int nt = 0; nt < NT; ++nt) {
        const u32* wr = Wt + (size_t)(nt * 16 + r15) * 64 + quad * 4;
#pragma unroll
        for (int ks = 0; ks < 4; ++ks) {
            bfrag bf = as_bfrag(*(const uint4*)(wr + ks * 16));
            acc[0][nt] = __builtin_amdgcn_mfma_f32_16x16x32_bf16(bf, af[0][ks], acc[0][nt], 0, 0, 0);
            acc[1][nt] = __builtin_amdgcn_mfma_f32_16x16x32_bf16(bf, af[1][ks], acc[1][nt], 0, 0, 0);
        }
    }

#pragma unroll
    for (int mi = 0; mi < 2; ++mi) {
        int row = rowbase + mi * 16 + r15;
        if (row < n) {
            u32* cp = C + (size_t)row * (OUT / 2);
#pragma unroll
            for (int nt = 0; nt < NT; ++nt) {
                uint2 p;
                p.x = pack_bf16(acc[mi][nt][0], acc[mi][nt][1]);
                p.y = pack_bf16(acc[mi][nt][2], acc[mi][nt][3]);
                *(uint2*)(cp + nt * 8 + quad * 2) = p;
            }
        }
    }
}

// ---------------- atomic-free CSR build ----------------

// Per-block LDS histogram over coarse bins (dst>>8) -> bc[bin][block].
// Blocks >= nb3 run prep_w; block 0 writes bc[M] = E.
__global__ __launch_bounds__(256) void count_bins_pw(const int* __restrict__ dst,
                                                     int* __restrict__ bc,
                                                     int E, int nbin, int nb3, int M,
                                                     const float* __restrict__ W1,
                                                     const float* __restrict__ W2,
                                                     u32* __restrict__ W1t,
                                                     u32* __restrict__ W2t) {
    __shared__ int hist[512];
    if (blockIdx.x >= (unsigned)nb3) {
        prep_w_chunk((blockIdx.x - nb3) * 256 + threadIdx.x, W1, W2, W1t, W2t);
        return;
    }
    if (blockIdx.x == 0 && threadIdx.x == 0) bc[M] = E;
    for (int t = threadIdx.x; t < nbin; t += 256) hist[t] = 0;
    __syncthreads();
    const int base = blockIdx.x * 2048 + threadIdx.x;
#pragma unroll
    for (int k = 0; k < 8; ++k) {
        int e = base + k * 256;
        if (e < E) atomicAdd(&hist[dst[e] >> 8], 1);
    }
    __syncthreads();
    for (int t = threadIdx.x; t < nbin; t += 256)
        bc[(size_t)t * nb3 + blockIdx.x] = hist[t];
}

// M-scan phase 1: per-1024-chunk sums.
__global__ __launch_bounds__(1024) void scan_reduce_g(const int* __restrict__ a,
                                                      int* __restrict__ bsum, int M) {
    __shared__ int wsum[16];
    int i = blockIdx.x * 1024 + threadIdx.x;
    int v = (i < M) ? a[i] : 0;
#pragma unroll
    for (int off = 32; off > 0; off >>= 1) v += __shfl_down(v, off);
    const int lane = threadIdx.x & 63;
    const int wid  = threadIdx.x >> 6;
    if (lane == 0) wsum[wid] = v;
    __syncthreads();
    if (threadIdx.x < 16) {
        int s = wsum[threadIdx.x];
#pragma unroll
        for (int off = 8; off > 0; off >>= 1) s += __shfl_down(s, off);
        if (threadIdx.x == 0) bsum[blockIdx.x] = s;
    }
}

// M-scan phase 2: in-place exclusive prefix, block offset self-computed.
__global__ __launch_bounds__(1024) void scan_apply_g2(int* __restrict__ a,
                                                      const int* __restrict__ bsum,
                                                      int nb, int M) {
    __shared__ int wsum[16];
    __shared__ int base_s;
    const int lane = threadIdx.x & 63;
    const int wid  = threadIdx.x >> 6;
    int pv = 0;
    for (int t = threadIdx.x; t < (int)blockIdx.x; t += 1024) pv += bsum[t];
#pragma unroll
    for (int off = 32; off > 0; off >>= 1) pv += __shfl_down(pv, off);
    if (lane == 0) wsum[wid] = pv;
    __syncthreads();
    if (threadIdx.x == 0) {
        int s = 0;
#pragma unroll
        for (int w = 0; w < 16; ++w) s += wsum[w];
        base_s = s;
    }
    __syncthreads();
    const int boff = base_s;
    int i = blockIdx.x * 1024 + threadIdx.x;
    int v = (i < M) ? a[i] : 0;
    int x = v;
#pragma unroll
    for (int off = 1; off < 64; off <<= 1) {
        int t = __shfl_up(x, off);
        if (lane >= off) x += t;
    }
    if (lane == 63) wsum[wid] = x;
    __syncthreads();
    if (wid == 0 && lane < 16) {
        int w = wsum[lane];
#pragma unroll
        for (int off = 1; off < 16; off <<= 1) {
            int t = __shfl_up(w, off);
            if (lane >= off) w += t;
        }
        wsum[lane] = w;
    }
    __syncthreads();
    int wave_excl = (wid == 0) ? 0 : wsum[wid - 1];
    if (i < M) a[i] = boff + wave_excl + (x - v);
}

// Scatter edges into per-(bin,block) reserved ranges via LDS cursors.
// Record: (dst&255)<<17 | src  (25 bits).
__global__ __launch_bounds__(256) void scatter_bins(const int* __restrict__ src,
                                                    const int* __restrict__ dst,
                                                    const int* __restrict__ offs,
                                                    u32* __restrict__ tmp,
                                                    int E, int nbin, int nb3) {
    __shared__ int cur[512];
    for (int t = threadIdx.x; t < nbin; t += 256)
        cur[t] = offs[(size_t)t * nb3 + blockIdx.x];
    __syncthreads();
    const int base = blockIdx.x * 2048 + threadIdx.x;
#pragma unroll
    for (int k = 0; k < 8; ++k) {
        int e = base + k * 256;
        if (e < E) {
            int d = dst[e];
            int pos = atomicAdd(&cur[d >> 8], 1);
            tmp[pos] = ((u32)(d & 255) << 17) | (u32)src[e];
        }
    }
}

// One block per bin: LDS 256-way hist + scan -> row_ptr/dinv directly
// (bin base offs[b*nb3] is the global edge prefix at node b*256).
__global__ __launch_bounds__(256) void bucket_hist(const u32* __restrict__ tmp,
                                                   const int* __restrict__ offs,
                                                   int* __restrict__ row_ptr,
                                                   float* __restrict__ dinv,
                                                   int n, int nb3, int E) {
    __shared__ int hist[256];
    __shared__ int wtot[4];
    const int b   = blockIdx.x;
    const int beg = offs[(size_t)b * nb3];
    const int end = offs[(size_t)(b + 1) * nb3];   // offs[M] = E for last bin
    hist[threadIdx.x] = 0;
    __syncthreads();
    for (int i = beg + threadIdx.x; i < end; i += 256)
        atomicAdd(&hist[tmp[i] >> 17], 1);
    __syncthreads();
    const int lane = threadIdx.x & 63;
    const int wid  = threadIdx.x >> 6;
    int v = hist[threadIdx.x];
    int x = v;
#pragma unroll
    for (int off = 1; off < 64; off <<= 1) {
        int t = __shfl_up(x, off);
        if (lane >= off) x += t;
    }
    if (lane == 63) wtot[wid] = x;
    __syncthreads();
    int wbase = 0;
    for (int w = 0; w < wid; ++w) wbase += wtot[w];
    const int rp = beg + wbase + x - v;
    const int d = b * 256 + threadIdx.x;
    if (d < n) {
        row_ptr[d] = rp;
        dinv[d]    = rsqrtf((float)v + 1.0f);
    }
    if (b == 0 && threadIdx.x == 0) row_ptr[n] = E;
}

// Fused: blocks < nbin scatter tmp2 records straight into ew (cursors from
// row_ptr; dinv valid across the launch boundary). Blocks >= nbin run gemm1
// (independent: reads x/W1t, writes h1u — CSR scratch lives on buf2 overlay).
__global__ __launch_bounds__(256) void bucket_ew_gemm1(
    const u32* __restrict__ tmp, const int* __restrict__ offs,
    const int* __restrict__ row_ptr, const float* __restrict__ dinv,
    u32* __restrict__ ew, int n, int nb3, int nbin,
    const float* __restrict__ x, const u32* __restrict__ W1t,
    u32* __restrict__ h1u) {
    if (blockIdx.x >= (unsigned)nbin) {
        gemm_body<128, false>(blockIdx.x - nbin, x, W1t, h1u, n);
        return;
    }
    __shared__ int   cur[256];
    __shared__ float sdi[256];
    const int b = blockIdx.x;
    const int t = threadIdx.x;
    const int beg = offs[(size_t)b * nb3];
    const int end = offs[(size_t)(b + 1) * nb3];
    const int d = b * 256 + t;
    cur[t] = row_ptr[(d <= n) ? d : n];
    sdi[t] = (d < n) ? dinv[d] : 0.0f;
    __syncthreads();
    for (int i = beg + t; i < end; i += 256) {
        u32 r = tmp[i];
        int k = r >> 17;
        int pos = atomicAdd(&cur[k], 1);
        u32 s = r & 0x1ffffu;
        ew[pos] = (s << 15) | pack_w(dinv[s] * sdi[k]);
    }
}

// ---------------- fused layer-1 gather + layer-2 GEMM ----------------

// Block = 4 waves = 32 nodes. Phase 1: wave wv gathers nodes wv*8..wv*8+8
// (unchanged R10 scalar-edge-fetch body), relu'd bf16 rows -> LDS (bit-
// identical to the old agg1b bytes). Phase 2: wave wv computes output
// col-tile wv (16 cols x 32 rows) from LDS A-frags + W2t, writes h2.
// LDS row pad = 68 dwords (16B-aligned, <=4-way bank aliasing on b128 reads).
__global__ __launch_bounds__(256) void gather128_gemm2(
    const u32* __restrict__ h, const float* __restrict__ dinv,
    const int* __restrict__ row_ptr, const u32* __restrict__ ew,
    const float* __restrict__ bias, const u32* __restrict__ W2t,
    u32* __restrict__ h2, int n) {
    __shared__ u32 sh_a[32][68];
    const int lane = threadIdx.x & 63;
    const int wv   = threadIdx.x >> 6;          // 0..3
    const int tile0 = blockIdx.x * 32;

    // ---- phase 1: gather 8 nodes per wave ----
    for (int ni = 0; ni < 8; ++ni) {
        const int r = wv * 8 + ni;
        int node = tile0 + r;
        if (node < n) {                          // wave-uniform
            node = __builtin_amdgcn_readfirstlane(node);
            const float dd  = dinv[node];
            const int   beg = __builtin_amdgcn_readfirstlane(row_ptr[node]);
            const int   end = __builtin_amdgcn_readfirstlane(row_ptr[node + 1]);

            u32 sv = h[(size_t)node * 64 + lane];
            float2 b = ((const float2*)bias)[lane];
            float acc0 = fmaf(bf_lo(sv) * dd, dd, b.x);
            float acc1 = fmaf(bf_hi(sv) * dd, dd, b.y);

            int j = beg;
            for (; j + 16 <= end; j += 16) {
                u32 ep[16];
#pragma unroll
                for (int k = 0; k < 16; ++k) ep[k] = ew[j + k];    // s_load
                u32 v[16];
#pragma unroll
                for (int k = 0; k < 16; ++k)
                    v[k] = h[((size_t)(ep[k] >> 15) << 6) + lane]; // saddr + lane
#pragma unroll
                for (int k = 0; k < 16; ++k) {
                    float wf = dec_w(ep[k]);                       // SALU decode
                    acc0 = fmaf(wf, bf_lo(v[k]), acc0);
                    acc1 = fmaf(wf, bf_hi(v[k]), acc1);
                }
            }
            for (; j < end; j += 8) {
                const int cnt = end - j;                           // 1..15 (SGPR)
                u32 ep[8];
#pragma unroll
                for (int k = 0; k < 8; ++k) {
                    int c = j + k;
                    ep[k] = ew[(c < end) ? c : end - 1];           // scalar clamp
                }
                u32 v[8];
#pragma unroll
                for (int k = 0; k < 8; ++k)
                    v[k] = h[((size_t)(ep[k] >> 15) << 6) + lane]; // pads L1-hot
#pragma unroll
                for (int k = 0; k < 8; ++k) {
                    float wf = (k < cnt) ? dec_w(ep[k]) : 0.0f;    // scalar select
                    acc0 = fmaf(wf, bf_lo(v[k]), acc0);
                    acc1 = fmaf(wf, bf_hi(v[k]), acc1);
                }
            }
            // relu + bf16 pack -> LDS (same bits as old agg1b)
            sh_a[r][lane] = pack_bf16(fmaxf(acc0, 0.0f), fmaxf(acc1, 0.0f));
        }
    }
    __syncthreads();

    // ---- phase 2: gemm2 col-tile wv (16 cols) for the block's 32 rows ----
    const int r15  = lane & 15;
    const int quad = lane >> 4;
    bfrag af[2][4];
#pragma unroll
    for (int mi = 0; mi < 2; ++mi)
#pragma unroll
        for (int ks = 0; ks < 4; ++ks)
            af[mi][ks] = as_bfrag(*(const uint4*)&sh_a[mi * 16 + r15][ks * 16 + quad * 4]);

    f4 acc[2];
    acc[0] = (f4)0.0f;
    acc[1] = (f4)0.0f;
    const u32* wr = W2t + (size_t)(wv * 16 + r15) * 64 + quad * 4;
#pragma unroll
    for (int ks = 0; ks < 4; ++ks) {
        bfrag bf = as_bfrag(*(const uint4*)(wr + ks * 16));
        acc[0] = __builtin_amdgcn_mfma_f32_16x16x32_bf16(bf, af[0][ks], acc[0], 0, 0, 0);
        acc[1] = __builtin_amdgcn_mfma_f32_16x16x32_bf16(bf, af[1][ks], acc[1], 0, 0, 0);
    }
#pragma unroll
    for (int mi = 0; mi < 2; ++mi) {
        int row = tile0 + mi * 16 + r15;
        if (row < n) {
            u32* cp = h2 + (size_t)row * 32 + wv * 8 + quad * 2;
            uint2 p;
            p.x = pack_bf16(acc[mi][0], acc[mi][1]);
            p.y = pack_bf16(acc[mi][2], acc[mi][3]);
            *(uint2*)cp = p;
        }
    }
}

// ---------------- layer-2 gather (unchanged R10 structure) ----------------

__global__ __launch_bounds__(256) void gather64(const u32* __restrict__ h,
                                                const float* __restrict__ dinv,
                                                const int* __restrict__ row_ptr,
                                                const u32* __restrict__ ew,
                                                const float* __restrict__ bias,
                                                float* __restrict__ outp, int n) {
    const int lane   = threadIdx.x & 63;
    const int lane32 = lane & 31;
    const int sub    = lane >> 5;
    int node = blockIdx.x * 4 + (threadIdx.x >> 6);
    if (node >= n) return;
    node = __builtin_amdgcn_readfirstlane(node);

    const int beg = __builtin_amdgcn_readfirstlane(row_ptr[node]);
    const int end = __builtin_amdgcn_readfirstlane(row_ptr[node + 1]);

    float acc0 = 0.0f, acc1 = 0.0f;
    if (sub == 0) {
        const float dd = dinv[node];
        u32 sv = h[(size_t)node * 32 + lane32];
        float2 b = ((const float2*)bias)[lane32];
        acc0 = fmaf(bf_lo(sv) * dd, dd, b.x);
        acc1 = fmaf(bf_hi(sv) * dd, dd, b.y);
    }

    int j = beg;
    for (; j + 16 <= end; j += 16) {
        u32 ep[16];
#pragma unroll
        for (int k = 0; k < 16; ++k) ep[k] = ew[j + k];        // s_load (merged)
        u32 v[8]; float wl[8];
#pragma unroll
        for (int p = 0; p < 8; ++p) {
            u32 e0 = ep[2 * p], e1 = ep[2 * p + 1];
            u32 so = sub ? (e1 >> 15) : (e0 >> 15);            // cndmask
            wl[p]  = sub ? dec_w(e1) : dec_w(e0);              // cndmask
            v[p]   = h[((size_t)so << 5) + lane32];
        }
#pragma unroll
        for (int p = 0; p < 8; ++p) {
            acc0 = fmaf(wl[p], bf_lo(v[p]), acc0);
            acc1 = fmaf(wl[p], bf_hi(v[p]), acc1);
        }
    }
    for (; j < end; j += 8) {
        const int cnt = end - j;                               // 1..15 (SGPR)
        u32 ep[8];
#pragma unroll
        for (int k = 0; k < 8; ++k) {
            int c = j + k;
            ep[k] = ew[(c < end) ? c : end - 1];               // scalar clamp
        }
        u32 v[4]; float wl[4];
#pragma unroll
        for (int p = 0; p < 4; ++p) {
            u32 e0 = ep[2 * p], e1 = ep[2 * p + 1];
            float w0 = (2 * p     < cnt) ? dec_w(e0) : 0.0f;   // scalar select
            float w1 = (2 * p + 1 < cnt) ? dec_w(e1) : 0.0f;
            u32 so = sub ? (e1 >> 15) : (e0 >> 15);
            wl[p]  = sub ? w1 : w0;
            v[p]   = h[((size_t)so << 5) + lane32];            // pads: L1-hot row
        }
#pragma unroll
        for (int p = 0; p < 4; ++p) {
            acc0 = fmaf(wl[p], bf_lo(v[p]), acc0);
            acc1 = fmaf(wl[p], bf_hi(v[p]), acc1);
        }
    }

    acc0 += __shfl_xor(acc0, 32);
    acc1 += __shfl_xor(acc1, 32);
    if (sub == 0)
        ((float2*)(outp + (size_t)node * 64))[lane32] = make_float2(acc0, acc1);
}

extern "C" void kernel_launch(void* const* d_in, const int* in_sizes, int n_in,
                              void* d_out, int out_size, void* d_ws, size_t ws_size,
                              hipStream_t stream) {
    const float* x  = (const float*)d_in[0];
    const int*   ei = (const int*)d_in[1];
    const float* W1 = (const float*)d_in[2];
    const float* b1 = (const float*)d_in[3];
    const float* W2 = (const float*)d_in[4];
    const float* b2 = (const float*)d_in[5];
    float*       out = (float*)d_out;

    const int n = in_sizes[0] / 128;   // 100000
    const int E = in_sizes[1] / 2;     // 1600000
    const int* srcv = ei;
    const int* dstv = ei + E;

    const int NP = 102400;
    u32* wsd = (u32*)d_ws;
    float* dinv    = (float*)wsd;                        // NP
    int*   row_ptr = (int*)(wsd + NP);                   // NP
    u32*   ew      = wsd + 2 * (size_t)NP;               // E
    u32*   h1u     = ew + E;                             // n*64 (gemm1 C / gather in; LIVE through fused kernel)
    u32*   buf2    = h1u + (size_t)n * 64;               // n*64 (CSR scratch overlay, then h2)
    u32*   W1t     = buf2 + (size_t)n * 64;              // 8192
    u32*   W2t     = W1t + 8192;                         // 4096
    u32*   h2u     = buf2;                               // gemm2 C: n*32 (CSR scratch dead by then)

    // CSR scratch — overlaid on buf2 (dead once bucket_ew_gemm1 completes):
    int*   bco  = (int*)buf2;                            // M+1 (305,763)
    u32*   tmp2 = buf2 + 400000;                         // E
    int*   bsum = (int*)(buf2 + 2200000);                // 512

    const int NBIN = (n + 255) >> 8;          // 391
    const int NB3  = (E + 2047) / 2048;       // 782
    const int M    = NBIN * NB3;              // 305,762
    const int MB   = (M + 1023) / 1024;       // 299

    const int gblocks = (n + 127) / 128;      // 782

    // --- CSR build (no global atomics) + fused gemm1 ---
    count_bins_pw<<<NB3 + 48, 256, 0, stream>>>(dstv, bco, E, NBIN, NB3, M,
                                                W1, W2, W1t, W2t);
    scan_reduce_g<<<MB, 1024, 0, stream>>>(bco, bsum, M);
    scan_apply_g2<<<MB, 1024, 0, stream>>>(bco, bsum, MB, M);
    scatter_bins<<<NB3, 256, 0, stream>>>(srcv, dstv, bco, tmp2, E, NBIN, NB3);
    bucket_hist<<<NBIN, 256, 0, stream>>>(tmp2, bco, row_ptr, dinv, n, NB3, E);
    bucket_ew_gemm1<<<NBIN + gblocks, 256, 0, stream>>>(tmp2, bco, row_ptr, dinv,
                                                        ew, n, NB3, NBIN,
                                                        x, W1t, h1u);

    // --- fused layer-1 gather + layer-2 GEMM ---
    gather128_gemm2<<<(n + 31) / 32, 256, 0, stream>>>(h1u, dinv, row_ptr, ew,
                                                       b1, W2t, h2u, n);

    // --- layer-2 gather ---
    gather64<<<(n + 3) / 4, 256, 0, stream>>>(h2u, dinv, row_ptr, ew, b2, out, n);
}

// Round 12
// 279.665 us; speedup vs baseline: 3.9034x; 1.0130x over previous
//
#include <hip/hip_runtime.h>

// GCN 2-layer. R6: bf16-MFMA GEMMs (no LDS, operand-swap epilogue). R9:
// atomic-free CSR (two-level bucket sort; device fetch-add ~24 Gops/s wall).
// R10: scalar edge fetch in gathers. R11 (reverted): slab slicing. R13
// (reverted): cooperative CSR. R14: bucket emits row_ptr/dinv directly.
// R15: bucket_ew scatters straight into ew, fused with gemm1. R16:
// gather128 FUSED with gemm2 (agg rows in LDS, one barrier, per-wave 16-col
// MFMA tile). R17: fused phase-1 node assignment made DYNAMIC (LDS
// work-steal counter + readfirstlane broadcast) — R16's static 8-node
// bundles made the barrier wait on max-of-4 degree sums (occupancy 70->57%,
// BW 3.85->3.3 TB/s); balancing recovers it. Per-node FP order unchanged ->
// bit-identical. R17b: resubmit after infra failure; work-steal loop made
// provably bounded (<=40 iters) — no arithmetic change.
// 4B edge payload src(17b)|ws15. Features bf16-pair packed.

typedef unsigned int u32;
using bfrag = __attribute__((ext_vector_type(8))) short;   // 8 bf16 (4 VGPRs)
using f4    = __attribute__((ext_vector_type(4))) float;   // 4 fp32 acc

__device__ inline u32 pack_bf16(float a, float b) {
    u32 ua = __float_as_uint(a);
    u32 ub = __float_as_uint(b);
    ua += 0x7fffu + ((ua >> 16) & 1u);   // RNE
    ub += 0x7fffu + ((ub >> 16) & 1u);
    return (ua >> 16) | (ub & 0xffff0000u);
}
__device__ inline float bf_lo(u32 v) { return __uint_as_float(v << 16); }
__device__ inline float bf_hi(u32 v) { return __uint_as_float(v & 0xffff0000u); }

// w in [2^-8, 1] -> 15 bits: ws = (bits(w) + rnd - 0x3B800000) >> 12.
__device__ inline u32 pack_w(float w) {
    u32 b = __float_as_uint(w) + 0x800u;       // round mantissa at 11 bits
    if (b < 0x3B800000u) b = 0x3B800000u;      // clamp to 2^-8 (unreachable)
    if (b > 0x3F800000u) b = 0x3F800000u;      // clamp to 1.0
    return (b - 0x3B800000u) >> 12;            // 15 bits
}
__device__ inline float dec_w(u32 e) {
    return __uint_as_float(((e & 0x7fffu) << 12) + 0x3B800000u);
}

__device__ inline bfrag as_bfrag(uint4 v) {
    union { uint4 u; bfrag b; } x; x.u = v; return x.b;
}

__device__ inline void prep_w_chunk(int idx, const float* __restrict__ W1,
                                    const float* __restrict__ W2,
                                    u32* __restrict__ W1t, u32* __restrict__ W2t) {
    if (idx < 128 * 64) {
        int nr = idx >> 6, kd = idx & 63;
        W1t[idx] = pack_bf16(W1[(2 * kd) * 128 + nr], W1[(2 * kd + 1) * 128 + nr]);
    } else if (idx < 128 * 64 + 64 * 64) {
        int i = idx - 128 * 64;
        int nr = i >> 6, kd = i & 63;
        W2t[i] = pack_bf16(W2[(2 * kd) * 64 + nr], W2[(2 * kd + 1) * 64 + nr]);
    }
}

// ---------------- GEMM body (used by fused gemm1) --------

// C[n][OUT] bf16-packed = A[n][128] @ W[128][OUT], via 16x16x32 bf16 MFMA.
// Operand swap: mfma(w_frag, a_frag) -> lane holds 4 consecutive C-cols.
template <int OUT, bool ABF>
__device__ inline void gemm_body(int bid, const void* __restrict__ Ap,
                                 const u32* __restrict__ Wt,
                                 u32* __restrict__ C, int n) {
    constexpr int NT = OUT / 16;
    const int lane = threadIdx.x & 63;
    const int wv   = threadIdx.x >> 6;
    const int r15  = lane & 15;
    const int quad = lane >> 4;
    const int rowbase = bid * 128 + wv * 32;

    bfrag af[2][4];
#pragma unroll
    for (int mi = 0; mi < 2; ++mi) {
        int row = rowbase + mi * 16 + r15;
        row = (row < n) ? row : (n - 1);
        if constexpr (ABF) {
            const u32* ar = (const u32*)Ap + (size_t)row * 64 + quad * 4;
#pragma unroll
            for (int ks = 0; ks < 4; ++ks)
                af[mi][ks] = as_bfrag(*(const uint4*)(ar + ks * 16));
        } else {
            const float* arf = (const float*)Ap + (size_t)row * 128 + quad * 8;
#pragma unroll
            for (int ks = 0; ks < 4; ++ks) {
                float4 v0 = *(const float4*)(arf + ks * 32);
                float4 v1 = *(const float4*)(arf + ks * 32 + 4);
                uint4 p;
                p.x = pack_bf16(v0.x, v0.y);
                p.y = pack_bf16(v0.z, v0.w);
                p.z = pack_bf16(v1.x, v1.y);
                p.w = pack_bf16(v1.z, v1.w);
                af[mi][ks] = as_bfrag(p);
            }
        }
    }

    f4 acc[2][NT];
#pragma unroll
    for (int mi = 0; mi < 2; ++mi)
#pragma unroll
        for (int nt = 0; nt < NT; ++nt) acc[mi][nt] = (f4)0.0f;

#pragma unroll
    for (int nt = 0; nt < NT; ++nt) {
        const u32* wr = Wt + (size_t)(nt * 16 + r15) * 64 + quad * 4;
#pragma unroll
        for (int ks = 0; ks < 4; ++ks) {
            bfrag bf = as_bfrag(*(const uint4*)(wr + ks * 16));
            acc[0][nt] = __builtin_amdgcn_mfma_f32_16x16x32_bf16(bf, af[0][ks], acc[0][nt], 0, 0, 0);
            acc[1][nt] = __builtin_amdgcn_mfma_f32_16x16x32_bf16(bf, af[1][ks], acc[1][nt], 0, 0, 0);
        }
    }

#pragma unroll
    for (int mi = 0; mi < 2; ++mi) {
        int row = rowbase + mi * 16 + r15;
        if (row < n) {
            u32* cp = C + (size_t)row * (OUT / 2);
#pragma unroll
            for (int nt = 0; nt < NT; ++nt) {
                uint2 p;
                p.x = pack_bf16(acc[mi][nt][0], acc[mi][nt][1]);
                p.y = pack_bf16(acc[mi][nt][2], acc[mi][nt][3]);
                *(uint2*)(cp + nt * 8 + quad * 2) = p;
            }
        }
    }
}

// ---------------- atomic-free CSR build ----------------

// Per-block LDS histogram over coarse bins (dst>>8) -> bc[bin][block].
// Blocks >= nb3 run prep_w; block 0 writes bc[M] = E.
__global__ __launch_bounds__(256) void count_bins_pw(const int* __restrict__ dst,
                                                     int* __restrict__ bc,
                                                     int E, int nbin, int nb3, int M,
                                                     const float* __restrict__ W1,
                                                     const float* __restrict__ W2,
                                                     u32* __restrict__ W1t,
                                                     u32* __restrict__ W2t) {
    __shared__ int hist[512];
    if (blockIdx.x >= (unsigned)nb3) {
        prep_w_chunk((blockIdx.x - nb3) * 256 + threadIdx.x, W1, W2, W1t, W2t);
        return;
    }
    if (blockIdx.x == 0 && threadIdx.x == 0) bc[M] = E;
    for (int t = threadIdx.x; t < nbin; t += 256) hist[t] = 0;
    __syncthreads();
    const int base = blockIdx.x * 2048 + threadIdx.x;
#pragma unroll
    for (int k = 0; k < 8; ++k) {
        int e = base + k * 256;
        if (e < E) atomicAdd(&hist[dst[e] >> 8], 1);
    }
    __syncthreads();
    for (int t = threadIdx.x; t < nbin; t += 256)
        bc[(size_t)t * nb3 + blockIdx.x] = hist[t];
}

// M-scan phase 1: per-1024-chunk sums.
__global__ __launch_bounds__(1024) void scan_reduce_g(const int* __restrict__ a,
                                                      int* __restrict__ bsum, int M) {
    __shared__ int wsum[16];
    int i = blockIdx.x * 1024 + threadIdx.x;
    int v = (i < M) ? a[i] : 0;
#pragma unroll
    for (int off = 32; off > 0; off >>= 1) v += __shfl_down(v, off);
    const int lane = threadIdx.x & 63;
    const int wid  = threadIdx.x >> 6;
    if (lane == 0) wsum[wid] = v;
    __syncthreads();
    if (threadIdx.x < 16) {
        int s = wsum[threadIdx.x];
#pragma unroll
        for (int off = 8; off > 0; off >>= 1) s += __shfl_down(s, off);
        if (threadIdx.x == 0) bsum[blockIdx.x] = s;
    }
}

// M-scan phase 2: in-place exclusive prefix, block offset self-computed.
__global__ __launch_bounds__(1024) void scan_apply_g2(int* __restrict__ a,
                                                      const int* __restrict__ bsum,
                                                      int nb, int M) {
    __shared__ int wsum[16];
    __shared__ int base_s;
    const int lane = threadIdx.x & 63;
    const int wid  = threadIdx.x >> 6;
    int pv = 0;
    for (int t = threadIdx.x; t < (int)blockIdx.x; t += 1024) pv += bsum[t];
#pragma unroll
    for (int off = 32; off > 0; off >>= 1) pv += __shfl_down(pv, off);
    if (lane == 0) wsum[wid] = pv;
    __syncthreads();
    if (threadIdx.x == 0) {
        int s = 0;
#pragma unroll
        for (int w = 0; w < 16; ++w) s += wsum[w];
        base_s = s;
    }
    __syncthreads();
    const int boff = base_s;
    int i = blockIdx.x * 1024 + threadIdx.x;
    int v = (i < M) ? a[i] : 0;
    int x = v;
#pragma unroll
    for (int off = 1; off < 64; off <<= 1) {
        int t = __shfl_up(x, off);
        if (lane >= off) x += t;
    }
    if (lane == 63) wsum[wid] = x;
    __syncthreads();
    if (wid == 0 && lane < 16) {
        int w = wsum[lane];
#pragma unroll
        for (int off = 1; off < 16; off <<= 1) {
            int t = __shfl_up(w, off);
            if (lane >= off) w += t;
        }
        wsum[lane] = w;
    }
    __syncthreads();
    int wave_excl = (wid == 0) ? 0 : wsum[wid - 1];
    if (i < M) a[i] = boff + wave_excl + (x - v);
}

// Scatter edges into per-(bin,block) reserved ranges via LDS cursors.
// Record: (dst&255)<<17 | src  (25 bits).
__global__ __launch_bounds__(256) void scatter_bins(const int* __restrict__ src,
                                                    const int* __restrict__ dst,
                                                    const int* __restrict__ offs,
                                                    u32* __restrict__ tmp,
                                                    int E, int nbin, int nb3) {
    __shared__ int cur[512];
    for (int t = threadIdx.x; t < nbin; t += 256)
        cur[t] = offs[(size_t)t * nb3 + blockIdx.x];
    __syncthreads();
    const int base = blockIdx.x * 2048 + threadIdx.x;
#pragma unroll
    for (int k = 0; k < 8; ++k) {
        int e = base + k * 256;
        if (e < E) {
            int d = dst[e];
            int pos = atomicAdd(&cur[d >> 8], 1);
            tmp[pos] = ((u32)(d & 255) << 17) | (u32)src[e];
        }
    }
}

// One block per bin: LDS 256-way hist + scan -> row_ptr/dinv directly
// (bin base offs[b*nb3] is the global edge prefix at node b*256).
__global__ __launch_bounds__(256) void bucket_hist(const u32* __restrict__ tmp,
                                                   const int* __restrict__ offs,
                                                   int* __restrict__ row_ptr,
                                                   float* __restrict__ dinv,
                                                   int n, int nb3, int E) {
    __shared__ int hist[256];
    __shared__ int wtot[4];
    const int b   = blockIdx.x;
    const int beg = offs[(size_t)b * nb3];
    const int end = offs[(size_t)(b + 1) * nb3];   // offs[M] = E for last bin
    hist[threadIdx.x] = 0;
    __syncthreads();
    for (int i = beg + threadIdx.x; i < end; i += 256)
        atomicAdd(&hist[tmp[i] >> 17], 1);
    __syncthreads();
    const int lane = threadIdx.x & 63;
    const int wid  = threadIdx.x >> 6;
    int v = hist[threadIdx.x];
    int x = v;
#pragma unroll
    for (int off = 1; off < 64; off <<= 1) {
        int t = __shfl_up(x, off);
        if (lane >= off) x += t;
    }
    if (lane == 63) wtot[wid] = x;
    __syncthreads();
    int wbase = 0;
    for (int w = 0; w < wid; ++w) wbase += wtot[w];
    const int rp = beg + wbase + x - v;
    const int d = b * 256 + threadIdx.x;
    if (d < n) {
        row_ptr[d] = rp;
        dinv[d]    = rsqrtf((float)v + 1.0f);
    }
    if (b == 0 && threadIdx.x == 0) row_ptr[n] = E;
}

// Fused: blocks < nbin scatter tmp2 records straight into ew (cursors from
// row_ptr; dinv valid across the launch boundary). Blocks >= nbin run gemm1
// (independent: reads x/W1t, writes h1u — CSR scratch lives on buf2 overlay).
__global__ __launch_bounds__(256) void bucket_ew_gemm1(
    const u32* __restrict__ tmp, const int* __restrict__ offs,
    const int* __restrict__ row_ptr, const float* __restrict__ dinv,
    u32* __restrict__ ew, int n, int nb3, int nbin,
    const float* __restrict__ x, const u32* __restrict__ W1t,
    u32* __restrict__ h1u) {
    if (blockIdx.x >= (unsigned)nbin) {
        gemm_body<128, false>(blockIdx.x - nbin, x, W1t, h1u, n);
        return;
    }
    __shared__ int   cur[256];
    __shared__ float sdi[256];
    const int b = blockIdx.x;
    const int t = threadIdx.x;
    const int beg = offs[(size_t)b * nb3];
    const int end = offs[(size_t)(b + 1) * nb3];
    const int d = b * 256 + t;
    cur[t] = row_ptr[(d <= n) ? d : n];
    sdi[t] = (d < n) ? dinv[d] : 0.0f;
    __syncthreads();
    for (int i = beg + t; i < end; i += 256) {
        u32 r = tmp[i];
        int k = r >> 17;
        int pos = atomicAdd(&cur[k], 1);
        u32 s = r & 0x1ffffu;
        ew[pos] = (s << 15) | pack_w(dinv[s] * sdi[k]);
    }
}

// ---------------- fused layer-1 gather + layer-2 GEMM ----------------

// Block = 4 waves = 32 nodes. Phase 1: DYNAMIC node pickup — wave's lane 0
// grabs row r from an LDS counter (readfirstlane broadcast), gathers node
// tile0+r (unchanged R10 scalar-edge-fetch body), relu'd bf16 row -> sh_a[r].
// Balances the barrier wait (R16's static 8-node bundles cost max-of-4
// degree-sum imbalance). Per-node FP order unchanged -> bit-identical.
// Loop is provably bounded: 4 waves x <=36 observed counter values < 40.
// Phase 2: wave wv computes output col-tile wv (16 cols x 32 rows) from LDS
// A-frags + W2t, writes h2. LDS row pad = 68 dwords (16B-aligned).
__global__ __launch_bounds__(256) void gather128_gemm2(
    const u32* __restrict__ h, const float* __restrict__ dinv,
    const int* __restrict__ row_ptr, const u32* __restrict__ ew,
    const float* __restrict__ bias, const u32* __restrict__ W2t,
    u32* __restrict__ h2, int n) {
    __shared__ u32 sh_a[32][68];
    __shared__ int wcnt;
    const int lane = threadIdx.x & 63;
    const int wv   = threadIdx.x >> 6;          // 0..3
    const int tile0 = blockIdx.x * 32;
    if (threadIdx.x == 0) wcnt = 0;
    __syncthreads();

    // ---- phase 1: work-steal gather, 32 rows per block ----
    const float2 b = ((const float2*)bias)[lane];
    for (int it = 0; it < 40; ++it) {           // bounded (see header comment)
        int r = 0;
        if (lane == 0) r = atomicAdd(&wcnt, 1);
        r = __builtin_amdgcn_readfirstlane(r);
        if (r >= 32) break;
        const int node = tile0 + r;
        if (node >= n) continue;

        const float dd  = dinv[node];
        const int   beg = __builtin_amdgcn_readfirstlane(row_ptr[node]);
        const int   end = __builtin_amdgcn_readfirstlane(row_ptr[node + 1]);

        u32 sv = h[(size_t)node * 64 + lane];
        float acc0 = fmaf(bf_lo(sv) * dd, dd, b.x);
        float acc1 = fmaf(bf_hi(sv) * dd, dd, b.y);

        int j = beg;
        for (; j + 16 <= end; j += 16) {
            u32 ep[16];
#pragma unroll
            for (int k = 0; k < 16; ++k) ep[k] = ew[j + k];    // s_load (merged)
            u32 v[16];
#pragma unroll
            for (int k = 0; k < 16; ++k)
                v[k] = h[((size_t)(ep[k] >> 15) << 6) + lane]; // saddr + lane
#pragma unroll
            for (int k = 0; k < 16; ++k) {
                float wf = dec_w(ep[k]);                       // SALU decode
                acc0 = fmaf(wf, bf_lo(v[k]), acc0);
                acc1 = fmaf(wf, bf_hi(v[k]), acc1);
            }
        }
        for (; j < end; j += 8) {
            const int cnt = end - j;                           // 1..15 (SGPR)
            u32 ep[8];
#pragma unroll
            for (int k = 0; k < 8; ++k) {
                int c = j + k;
                ep[k] = ew[(c < end) ? c : end - 1];           // scalar clamp
            }
            u32 v[8];
#pragma unroll
            for (int k = 0; k < 8; ++k)
                v[k] = h[((size_t)(ep[k] >> 15) << 6) + lane]; // pads: L1-hot row
#pragma unroll
            for (int k = 0; k < 8; ++k) {
                float wf = (k < cnt) ? dec_w(ep[k]) : 0.0f;    // scalar select
                acc0 = fmaf(wf, bf_lo(v[k]), acc0);
                acc1 = fmaf(wf, bf_hi(v[k]), acc1);
            }
        }
        // relu + bf16 pack -> LDS (same bits as old agg1b)
        sh_a[r][lane] = pack_bf16(fmaxf(acc0, 0.0f), fmaxf(acc1, 0.0f));
    }
    __syncthreads();

    // ---- phase 2: gemm2 col-tile wv (16 cols) for the block's 32 rows ----
    const int r15  = lane & 15;
    const int quad = lane >> 4;
    bfrag af[2][4];
#pragma unroll
    for (int mi = 0; mi < 2; ++mi)
#pragma unroll
        for (int ks = 0; ks < 4; ++ks)
            af[mi][ks] = as_bfrag(*(const uint4*)&sh_a[mi * 16 + r15][ks * 16 + quad * 4]);

    f4 acc[2];
    acc[0] = (f4)0.0f;
    acc[1] = (f4)0.0f;
    const u32* wr = W2t + (size_t)(wv * 16 + r15) * 64 + quad * 4;
#pragma unroll
    for (int ks = 0; ks < 4; ++ks) {
        bfrag bf = as_bfrag(*(const uint4*)(wr + ks * 16));
        acc[0] = __builtin_amdgcn_mfma_f32_16x16x32_bf16(bf, af[0][ks], acc[0], 0, 0, 0);
        acc[1] = __builtin_amdgcn_mfma_f32_16x16x32_bf16(bf, af[1][ks], acc[1], 0, 0, 0);
    }
#pragma unroll
    for (int mi = 0; mi < 2; ++mi) {
        int row = tile0 + mi * 16 + r15;
        if (row < n) {
            u32* cp = h2 + (size_t)row * 32 + wv * 8 + quad * 2;
            uint2 p;
            p.x = pack_bf16(acc[mi][0], acc[mi][1]);
            p.y = pack_bf16(acc[mi][2], acc[mi][3]);
            *(uint2*)cp = p;
        }
    }
}

// ---------------- layer-2 gather (unchanged R10 structure) ----------------

__global__ __launch_bounds__(256) void gather64(const u32* __restrict__ h,
                                                const float* __restrict__ dinv,
                                                const int* __restrict__ row_ptr,
                                                const u32* __restrict__ ew,
                                                const float* __restrict__ bias,
                                                float* __restrict__ outp, int n) {
    const int lane   = threadIdx.x & 63;
    const int lane32 = lane & 31;
    const int sub    = lane >> 5;
    int node = blockIdx.x * 4 + (threadIdx.x >> 6);
    if (node >= n) return;
    node = __builtin_amdgcn_readfirstlane(node);

    const int beg = __builtin_amdgcn_readfirstlane(row_ptr[node]);
    const int end = __builtin_amdgcn_readfirstlane(row_ptr[node + 1]);

    float acc0 = 0.0f, acc1 = 0.0f;
    if (sub == 0) {
        const float dd = dinv[node];
        u32 sv = h[(size_t)node * 32 + lane32];
        float2 b = ((const float2*)bias)[lane32];
        acc0 = fmaf(bf_lo(sv) * dd, dd, b.x);
        acc1 = fmaf(bf_hi(sv) * dd, dd, b.y);
    }

    int j = beg;
    for (; j + 16 <= end; j += 16) {
        u32 ep[16];
#pragma unroll
        for (int k = 0; k < 16; ++k) ep[k] = ew[j + k];        // s_load (merged)
        u32 v[8]; float wl[8];
#pragma unroll
        for (int p = 0; p < 8; ++p) {
            u32 e0 = ep[2 * p], e1 = ep[2 * p + 1];
            u32 so = sub ? (e1 >> 15) : (e0 >> 15);            // cndmask
            wl[p]  = sub ? dec_w(e1) : dec_w(e0);              // cndmask
            v[p]   = h[((size_t)so << 5) + lane32];
        }
#pragma unroll
        for (int p = 0; p < 8; ++p) {
            acc0 = fmaf(wl[p], bf_lo(v[p]), acc0);
            acc1 = fmaf(wl[p], bf_hi(v[p]), acc1);
        }
    }
    for (; j < end; j += 8) {
        const int cnt = end - j;                               // 1..15 (SGPR)
        u32 ep[8];
#pragma unroll
        for (int k = 0; k < 8; ++k) {
            int c = j + k;
            ep[k] = ew[(c < end) ? c : end - 1];               // scalar clamp
        }
        u32 v[4]; float wl[4];
#pragma unroll
        for (int p = 0; p < 4; ++p) {
            u32 e0 = ep[2 * p], e1 = ep[2 * p + 1];
            float w0 = (2 * p     < cnt) ? dec_w(e0) : 0.0f;   // scalar select
            float w1 = (2 * p + 1 < cnt) ? dec_w(e1) : 0.0f;
            u32 so = sub ? (e1 >> 15) : (e0 >> 15);
            wl[p]  = sub ? w1 : w0;
            v[p]   = h[((size_t)so << 5) + lane32];            // pads: L1-hot row
        }
#pragma unroll
        for (int p = 0; p < 4; ++p) {
            acc0 = fmaf(wl[p], bf_lo(v[p]), acc0);
            acc1 = fmaf(wl[p], bf_hi(v[p]), acc1);
        }
    }

    acc0 += __shfl_xor(acc0, 32);
    acc1 += __shfl_xor(acc1, 32);
    if (sub == 0)
        ((float2*)(outp + (size_t)node * 64))[lane32] = make_float2(acc0, acc1);
}

extern "C" void kernel_launch(void* const* d_in, const int* in_sizes, int n_in,
                              void* d_out, int out_size, void* d_ws, size_t ws_size,
                              hipStream_t stream) {
    const float* x  = (const float*)d_in[0];
    const int*   ei = (const int*)d_in[1];
    const float* W1 = (const float*)d_in[2];
    const float* b1 = (const float*)d_in[3];
    const float* W2 = (const float*)d_in[4];
    const float* b2 = (const float*)d_in[5];
    float*       out = (float*)d_out;

    const int n = in_sizes[0] / 128;   // 100000
    const int E = in_sizes[1] / 2;     // 1600000
    const int* srcv = ei;
    const int* dstv = ei + E;

    const int NP = 102400;
    u32* wsd = (u32*)d_ws;
    float* dinv    = (float*)wsd;                        // NP
    int*   row_ptr = (int*)(wsd + NP);                   // NP
    u32*   ew      = wsd + 2 * (size_t)NP;               // E
    u32*   h1u     = ew + E;                             // n*64 (gemm1 C / gather in; LIVE through fused kernel)
    u32*   buf2    = h1u + (size_t)n * 64;               // n*64 (CSR scratch overlay, then h2)
    u32*   W1t     = buf2 + (size_t)n * 64;              // 8192
    u32*   W2t     = W1t + 8192;                         // 4096
    u32*   h2u     = buf2;                               // gemm2 C: n*32 (CSR scratch dead by then)

    // CSR scratch — overlaid on buf2 (dead once bucket_ew_gemm1 completes):
    int*   bco  = (int*)buf2;                            // M+1 (305,763)
    u32*   tmp2 = buf2 + 400000;                         // E
    int*   bsum = (int*)(buf2 + 2200000);                // 512

    const int NBIN = (n + 255) >> 8;          // 391
    const int NB3  = (E + 2047) / 2048;       // 782
    const int M    = NBIN * NB3;              // 305,762
    const int MB   = (M + 1023) / 1024;       // 299

    const int gblocks = (n + 127) / 128;      // 782

    // --- CSR build (no global atomics) + fused gemm1 ---
    count_bins_pw<<<NB3 + 48, 256, 0, stream>>>(dstv, bco, E, NBIN, NB3, M,
                                                W1, W2, W1t, W2t);
    scan_reduce_g<<<MB, 1024, 0, stream>>>(bco, bsum, M);
    scan_apply_g2<<<MB, 1024, 0, stream>>>(bco, bsum, MB, M);
    scatter_bins<<<NB3, 256, 0, stream>>>(srcv, dstv, bco, tmp2, E, NBIN, NB3);
    bucket_hist<<<NBIN, 256, 0, stream>>>(tmp2, bco, row_ptr, dinv, n, NB3, E);
    bucket_ew_gemm1<<<NBIN + gblocks, 256, 0, stream>>>(tmp2, bco, row_ptr, dinv,
                                                        ew, n, NB3, NBIN,
                                                        x, W1t, h1u);

    // --- fused layer-1 gather + layer-2 GEMM ---
    gather128_gemm2<<<(n + 31) / 32, 256, 0, stream>>>(h1u, dinv, row_ptr, ew,
                                                       b1, W2t, h2u, n);

    // --- layer-2 gather ---
    gather64<<<(n + 3) / 4, 256, 0, stream>>>(h2u, dinv, row_ptr, ew, b2, out, n);
}

// Round 13
// 267.062 us; speedup vs baseline: 4.0876x; 1.0472x over previous
//
#include <hip/hip_runtime.h>

// GCN 2-layer. R6: bf16-MFMA GEMMs (no LDS, operand-swap epilogue). R9:
// atomic-free CSR (two-level bucket sort; device fetch-add ~24 Gops/s wall).
// R10: scalar edge fetch in gathers. R11 (reverted): slab slicing. R13
// (reverted): cooperative CSR. R14: bucket emits row_ptr/dinv directly.
// R15: bucket_ew scatters straight into ew, fused with gemm1. R16/R17:
// gather128 fused with gemm2 (LDS agg rows, work-steal phase 1). R18:
// count/scatter phases widened to 1024-thread blocks over 8192 edges
// (NB3 782->196): per-(bin,block) scatter runs grow 5.2->21 edges (~84B,
// line-grade) cutting the 32B-packet write pathology ~2.5x; M drops 4x
// (scans cheaper). Bucket phase keeps NBIN=391 blocks (parallelism intact).
// 4B edge payload src(17b)|ws15. Features bf16-pair packed.

typedef unsigned int u32;
using bfrag = __attribute__((ext_vector_type(8))) short;   // 8 bf16 (4 VGPRs)
using f4    = __attribute__((ext_vector_type(4))) float;   // 4 fp32 acc

__device__ inline u32 pack_bf16(float a, float b) {
    u32 ua = __float_as_uint(a);
    u32 ub = __float_as_uint(b);
    ua += 0x7fffu + ((ua >> 16) & 1u);   // RNE
    ub += 0x7fffu + ((ub >> 16) & 1u);
    return (ua >> 16) | (ub & 0xffff0000u);
}
__device__ inline float bf_lo(u32 v) { return __uint_as_float(v << 16); }
__device__ inline float bf_hi(u32 v) { return __uint_as_float(v & 0xffff0000u); }

// w in [2^-8, 1] -> 15 bits: ws = (bits(w) + rnd - 0x3B800000) >> 12.
__device__ inline u32 pack_w(float w) {
    u32 b = __float_as_uint(w) + 0x800u;       // round mantissa at 11 bits
    if (b < 0x3B800000u) b = 0x3B800000u;      // clamp to 2^-8 (unreachable)
    if (b > 0x3F800000u) b = 0x3F800000u;      // clamp to 1.0
    return (b - 0x3B800000u) >> 12;            // 15 bits
}
__device__ inline float dec_w(u32 e) {
    return __uint_as_float(((e & 0x7fffu) << 12) + 0x3B800000u);
}

__device__ inline bfrag as_bfrag(uint4 v) {
    union { uint4 u; bfrag b; } x; x.u = v; return x.b;
}

__device__ inline void prep_w_chunk(int idx, const float* __restrict__ W1,
                                    const float* __restrict__ W2,
                                    u32* __restrict__ W1t, u32* __restrict__ W2t) {
    if (idx < 128 * 64) {
        int nr = idx >> 6, kd = idx & 63;
        W1t[idx] = pack_bf16(W1[(2 * kd) * 128 + nr], W1[(2 * kd + 1) * 128 + nr]);
    } else if (idx < 128 * 64 + 64 * 64) {
        int i = idx - 128 * 64;
        int nr = i >> 6, kd = i & 63;
        W2t[i] = pack_bf16(W2[(2 * kd) * 64 + nr], W2[(2 * kd + 1) * 64 + nr]);
    }
}

// ---------------- GEMM body (used by fused gemm1) --------

// C[n][OUT] bf16-packed = A[n][128] @ W[128][OUT], via 16x16x32 bf16 MFMA.
// Operand swap: mfma(w_frag, a_frag) -> lane holds 4 consecutive C-cols.
template <int OUT, bool ABF>
__device__ inline void gemm_body(int bid, const void* __restrict__ Ap,
                                 const u32* __restrict__ Wt,
                                 u32* __restrict__ C, int n) {
    constexpr int NT = OUT / 16;
    const int lane = threadIdx.x & 63;
    const int wv   = threadIdx.x >> 6;
    const int r15  = lane & 15;
    const int quad = lane >> 4;
    const int rowbase = bid * 128 + wv * 32;

    bfrag af[2][4];
#pragma unroll
    for (int mi = 0; mi < 2; ++mi) {
        int row = rowbase + mi * 16 + r15;
        row = (row < n) ? row : (n - 1);
        if constexpr (ABF) {
            const u32* ar = (const u32*)Ap + (size_t)row * 64 + quad * 4;
#pragma unroll
            for (int ks = 0; ks < 4; ++ks)
                af[mi][ks] = as_bfrag(*(const uint4*)(ar + ks * 16));
        } else {
            const float* arf = (const float*)Ap + (size_t)row * 128 + quad * 8;
#pragma unroll
            for (int ks = 0; ks < 4; ++ks) {
                float4 v0 = *(const float4*)(arf + ks * 32);
                float4 v1 = *(const float4*)(arf + ks * 32 + 4);
                uint4 p;
                p.x = pack_bf16(v0.x, v0.y);
                p.y = pack_bf16(v0.z, v0.w);
                p.z = pack_bf16(v1.x, v1.y);
                p.w = pack_bf16(v1.z, v1.w);
                af[mi][ks] = as_bfrag(p);
            }
        }
    }

    f4 acc[2][NT];
#pragma unroll
    for (int mi = 0; mi < 2; ++mi)
#pragma unroll
        for (int nt = 0; nt < NT; ++nt) acc[mi][nt] = (f4)0.0f;

#pragma unroll
    for (int nt = 0; nt < NT; ++nt) {
        const u32* wr = Wt + (size_t)(nt * 16 + r15) * 64 + quad * 4;
#pragma unroll
        for (int ks = 0; ks < 4; ++ks) {
            bfrag bf = as_bfrag(*(const uint4*)(wr + ks * 16));
            acc[0][nt] = __builtin_amdgcn_mfma_f32_16x16x32_bf16(bf, af[0][ks], acc[0][nt], 0, 0, 0);
            acc[1][nt] = __builtin_amdgcn_mfma_f32_16x16x32_bf16(bf, af[1][ks], acc[1][nt], 0, 0, 0);
        }
    }

#pragma unroll
    for (int mi = 0; mi < 2; ++mi) {
        int row = rowbase + mi * 16 + r15;
        if (row < n) {
            u32* cp = C + (size_t)row * (OUT / 2);
#pragma unroll
            for (int nt = 0; nt < NT; ++nt) {
                uint2 p;
                p.x = pack_bf16(acc[mi][nt][0], acc[mi][nt][1]);
                p.y = pack_bf16(acc[mi][nt][2], acc[mi][nt][3]);
                *(uint2*)(cp + nt * 8 + quad * 2) = p;
            }
        }
    }
}

// ---------------- atomic-free CSR build ----------------

// 1024-thread blocks over 8192 edges: LDS histogram over coarse bins
// (dst>>8) -> bc[bin][block]. Blocks >= nb3 run prep_w (12 x 1024);
// block 0 writes bc[M] = E.
__global__ __launch_bounds__(1024) void count_bins_pw(const int* __restrict__ dst,
                                                      int* __restrict__ bc,
                                                      int E, int nbin, int nb3, int M,
                                                      const float* __restrict__ W1,
                                                      const float* __restrict__ W2,
                                                      u32* __restrict__ W1t,
                                                      u32* __restrict__ W2t) {
    __shared__ int hist[512];
    if (blockIdx.x >= (unsigned)nb3) {
        prep_w_chunk((blockIdx.x - nb3) * 1024 + threadIdx.x, W1, W2, W1t, W2t);
        return;
    }
    if (blockIdx.x == 0 && threadIdx.x == 0) bc[M] = E;
    for (int t = threadIdx.x; t < nbin; t += 1024) hist[t] = 0;
    __syncthreads();
    const int base = blockIdx.x * 8192 + threadIdx.x;
#pragma unroll
    for (int k = 0; k < 8; ++k) {
        int e = base + k * 1024;
        if (e < E) atomicAdd(&hist[dst[e] >> 8], 1);
    }
    __syncthreads();
    for (int t = threadIdx.x; t < nbin; t += 1024)
        bc[(size_t)t * nb3 + blockIdx.x] = hist[t];
}

// M-scan phase 1: per-1024-chunk sums.
__global__ __launch_bounds__(1024) void scan_reduce_g(const int* __restrict__ a,
                                                      int* __restrict__ bsum, int M) {
    __shared__ int wsum[16];
    int i = blockIdx.x * 1024 + threadIdx.x;
    int v = (i < M) ? a[i] : 0;
#pragma unroll
    for (int off = 32; off > 0; off >>= 1) v += __shfl_down(v, off);
    const int lane = threadIdx.x & 63;
    const int wid  = threadIdx.x >> 6;
    if (lane == 0) wsum[wid] = v;
    __syncthreads();
    if (threadIdx.x < 16) {
        int s = wsum[threadIdx.x];
#pragma unroll
        for (int off = 8; off > 0; off >>= 1) s += __shfl_down(s, off);
        if (threadIdx.x == 0) bsum[blockIdx.x] = s;
    }
}

// M-scan phase 2: in-place exclusive prefix, block offset self-computed.
__global__ __launch_bounds__(1024) void scan_apply_g2(int* __restrict__ a,
                                                      const int* __restrict__ bsum,
                                                      int nb, int M) {
    __shared__ int wsum[16];
    __shared__ int base_s;
    const int lane = threadIdx.x & 63;
    const int wid  = threadIdx.x >> 6;
    int pv = 0;
    for (int t = threadIdx.x; t < (int)blockIdx.x; t += 1024) pv += bsum[t];
#pragma unroll
    for (int off = 32; off > 0; off >>= 1) pv += __shfl_down(pv, off);
    if (lane == 0) wsum[wid] = pv;
    __syncthreads();
    if (threadIdx.x == 0) {
        int s = 0;
#pragma unroll
        for (int w = 0; w < 16; ++w) s += wsum[w];
        base_s = s;
    }
    __syncthreads();
    const int boff = base_s;
    int i = blockIdx.x * 1024 + threadIdx.x;
    int v = (i < M) ? a[i] : 0;
    int x = v;
#pragma unroll
    for (int off = 1; off < 64; off <<= 1) {
        int t = __shfl_up(x, off);
        if (lane >= off) x += t;
    }
    if (lane == 63) wsum[wid] = x;
    __syncthreads();
    if (wid == 0 && lane < 16) {
        int w = wsum[lane];
#pragma unroll
        for (int off = 1; off < 16; off <<= 1) {
            int t = __shfl_up(w, off);
            if (lane >= off) w += t;
        }
        wsum[lane] = w;
    }
    __syncthreads();
    int wave_excl = (wid == 0) ? 0 : wsum[wid - 1];
    if (i < M) a[i] = boff + wave_excl + (x - v);
}

// 1024-thread blocks over 8192 edges: scatter into per-(bin,block) reserved
// ranges via LDS cursors. Runs are ~21 edges (84B, line-grade).
// Record: (dst&255)<<17 | src  (25 bits).
__global__ __launch_bounds__(1024) void scatter_bins(const int* __restrict__ src,
                                                     const int* __restrict__ dst,
                                                     const int* __restrict__ offs,
                                                     u32* __restrict__ tmp,
                                                     int E, int nbin, int nb3) {
    __shared__ int cur[512];
    for (int t = threadIdx.x; t < nbin; t += 1024)
        cur[t] = offs[(size_t)t * nb3 + blockIdx.x];
    __syncthreads();
    const int base = blockIdx.x * 8192 + threadIdx.x;
#pragma unroll
    for (int k = 0; k < 8; ++k) {
        int e = base + k * 1024;
        if (e < E) {
            int d = dst[e];
            int pos = atomicAdd(&cur[d >> 8], 1);
            tmp[pos] = ((u32)(d & 255) << 17) | (u32)src[e];
        }
    }
}

// One block per bin: LDS 256-way hist + scan -> row_ptr/dinv directly
// (bin base offs[b*nb3] is the global edge prefix at node b*256).
__global__ __launch_bounds__(256) void bucket_hist(const u32* __restrict__ tmp,
                                                   const int* __restrict__ offs,
                                                   int* __restrict__ row_ptr,
                                                   float* __restrict__ dinv,
                                                   int n, int nb3, int E) {
    __shared__ int hist[256];
    __shared__ int wtot[4];
    const int b   = blockIdx.x;
    const int beg = offs[(size_t)b * nb3];
    const int end = offs[(size_t)(b + 1) * nb3];   // offs[M] = E for last bin
    hist[threadIdx.x] = 0;
    __syncthreads();
    for (int i = beg + threadIdx.x; i < end; i += 256)
        atomicAdd(&hist[tmp[i] >> 17], 1);
    __syncthreads();
    const int lane = threadIdx.x & 63;
    const int wid  = threadIdx.x >> 6;
    int v = hist[threadIdx.x];
    int x = v;
#pragma unroll
    for (int off = 1; off < 64; off <<= 1) {
        int t = __shfl_up(x, off);
        if (lane >= off) x += t;
    }
    if (lane == 63) wtot[wid] = x;
    __syncthreads();
    int wbase = 0;
    for (int w = 0; w < wid; ++w) wbase += wtot[w];
    const int rp = beg + wbase + x - v;
    const int d = b * 256 + threadIdx.x;
    if (d < n) {
        row_ptr[d] = rp;
        dinv[d]    = rsqrtf((float)v + 1.0f);
    }
    if (b == 0 && threadIdx.x == 0) row_ptr[n] = E;
}

// Fused: blocks < nbin scatter tmp2 records straight into ew (cursors from
// row_ptr; dinv valid across the launch boundary). Blocks >= nbin run gemm1
// (independent: reads x/W1t, writes h1u — CSR scratch lives on buf2 overlay).
__global__ __launch_bounds__(256) void bucket_ew_gemm1(
    const u32* __restrict__ tmp, const int* __restrict__ offs,
    const int* __restrict__ row_ptr, const float* __restrict__ dinv,
    u32* __restrict__ ew, int n, int nb3, int nbin,
    const float* __restrict__ x, const u32* __restrict__ W1t,
    u32* __restrict__ h1u) {
    if (blockIdx.x >= (unsigned)nbin) {
        gemm_body<128, false>(blockIdx.x - nbin, x, W1t, h1u, n);
        return;
    }
    __shared__ int   cur[256];
    __shared__ float sdi[256];
    const int b = blockIdx.x;
    const int t = threadIdx.x;
    const int beg = offs[(size_t)b * nb3];
    const int end = offs[(size_t)(b + 1) * nb3];
    const int d = b * 256 + t;
    cur[t] = row_ptr[(d <= n) ? d : n];
    sdi[t] = (d < n) ? dinv[d] : 0.0f;
    __syncthreads();
    for (int i = beg + t; i < end; i += 256) {
        u32 r = tmp[i];
        int k = r >> 17;
        int pos = atomicAdd(&cur[k], 1);
        u32 s = r & 0x1ffffu;
        ew[pos] = (s << 15) | pack_w(dinv[s] * sdi[k]);
    }
}

// ---------------- fused layer-1 gather + layer-2 GEMM ----------------

// Block = 4 waves = 32 nodes. Phase 1: dynamic node pickup via LDS counter
// (readfirstlane broadcast); unchanged R10 scalar-edge-fetch body; relu'd
// bf16 row -> sh_a[r]. Bounded loop (<=40 iters). Phase 2: wave wv computes
// output col-tile wv (16 cols x 32 rows) from LDS A-frags + W2t, writes h2.
__global__ __launch_bounds__(256) void gather128_gemm2(
    const u32* __restrict__ h, const float* __restrict__ dinv,
    const int* __restrict__ row_ptr, const u32* __restrict__ ew,
    const float* __restrict__ bias, const u32* __restrict__ W2t,
    u32* __restrict__ h2, int n) {
    __shared__ u32 sh_a[32][68];
    __shared__ int wcnt;
    const int lane = threadIdx.x & 63;
    const int wv   = threadIdx.x >> 6;          // 0..3
    const int tile0 = blockIdx.x * 32;
    if (threadIdx.x == 0) wcnt = 0;
    __syncthreads();

    // ---- phase 1: work-steal gather, 32 rows per block ----
    const float2 b = ((const float2*)bias)[lane];
    for (int it = 0; it < 40; ++it) {           // bounded
        int r = 0;
        if (lane == 0) r = atomicAdd(&wcnt, 1);
        r = __builtin_amdgcn_readfirstlane(r);
        if (r >= 32) break;
        const int node = tile0 + r;
        if (node >= n) continue;

        const float dd  = dinv[node];
        const int   beg = __builtin_amdgcn_readfirstlane(row_ptr[node]);
        const int   end = __builtin_amdgcn_readfirstlane(row_ptr[node + 1]);

        u32 sv = h[(size_t)node * 64 + lane];
        float acc0 = fmaf(bf_lo(sv) * dd, dd, b.x);
        float acc1 = fmaf(bf_hi(sv) * dd, dd, b.y);

        int j = beg;
        for (; j + 16 <= end; j += 16) {
            u32 ep[16];
#pragma unroll
            for (int k = 0; k < 16; ++k) ep[k] = ew[j + k];    // s_load (merged)
            u32 v[16];
#pragma unroll
            for (int k = 0; k < 16; ++k)
                v[k] = h[((size_t)(ep[k] >> 15) << 6) + lane]; // saddr + lane
#pragma unroll
            for (int k = 0; k < 16; ++k) {
                float wf = dec_w(ep[k]);                       // SALU decode
                acc0 = fmaf(wf, bf_lo(v[k]), acc0);
                acc1 = fmaf(wf, bf_hi(v[k]), acc1);
            }
        }
        for (; j < end; j += 8) {
            const int cnt = end - j;                           // 1..15 (SGPR)
            u32 ep[8];
#pragma unroll
            for (int k = 0; k < 8; ++k) {
                int c = j + k;
                ep[k] = ew[(c < end) ? c : end - 1];           // scalar clamp
            }
            u32 v[8];
#pragma unroll
            for (int k = 0; k < 8; ++k)
                v[k] = h[((size_t)(ep[k] >> 15) << 6) + lane]; // pads: L1-hot row
#pragma unroll
            for (int k = 0; k < 8; ++k) {
                float wf = (k < cnt) ? dec_w(ep[k]) : 0.0f;    // scalar select
                acc0 = fmaf(wf, bf_lo(v[k]), acc0);
                acc1 = fmaf(wf, bf_hi(v[k]), acc1);
            }
        }
        // relu + bf16 pack -> LDS (same bits as old agg1b)
        sh_a[r][lane] = pack_bf16(fmaxf(acc0, 0.0f), fmaxf(acc1, 0.0f));
    }
    __syncthreads();

    // ---- phase 2: gemm2 col-tile wv (16 cols) for the block's 32 rows ----
    const int r15  = lane & 15;
    const int quad = lane >> 4;
    bfrag af[2][4];
#pragma unroll
    for (int mi = 0; mi < 2; ++mi)
#pragma unroll
        for (int ks = 0; ks < 4; ++ks)
            af[mi][ks] = as_bfrag(*(const uint4*)&sh_a[mi * 16 + r15][ks * 16 + quad * 4]);

    f4 acc[2];
    acc[0] = (f4)0.0f;
    acc[1] = (f4)0.0f;
    const u32* wr = W2t + (size_t)(wv * 16 + r15) * 64 + quad * 4;
#pragma unroll
    for (int ks = 0; ks < 4; ++ks) {
        bfrag bf = as_bfrag(*(const uint4*)(wr + ks * 16));
        acc[0] = __builtin_amdgcn_mfma_f32_16x16x32_bf16(bf, af[0][ks], acc[0], 0, 0, 0);
        acc[1] = __builtin_amdgcn_mfma_f32_16x16x32_bf16(bf, af[1][ks], acc[1], 0, 0, 0);
    }
#pragma unroll
    for (int mi = 0; mi < 2; ++mi) {
        int row = tile0 + mi * 16 + r15;
        if (row < n) {
            u32* cp = h2 + (size_t)row * 32 + wv * 8 + quad * 2;
            uint2 p;
            p.x = pack_bf16(acc[mi][0], acc[mi][1]);
            p.y = pack_bf16(acc[mi][2], acc[mi][3]);
            *(uint2*)cp = p;
        }
    }
}

// ---------------- layer-2 gather (unchanged R10 structure) ----------------

__global__ __launch_bounds__(256) void gather64(const u32* __restrict__ h,
                                                const float* __restrict__ dinv,
                                                const int* __restrict__ row_ptr,
                                                const u32* __restrict__ ew,
                                                const float* __restrict__ bias,
                                                float* __restrict__ outp, int n) {
    const int lane   = threadIdx.x & 63;
    const int lane32 = lane & 31;
    const int sub    = lane >> 5;
    int node = blockIdx.x * 4 + (threadIdx.x >> 6);
    if (node >= n) return;
    node = __builtin_amdgcn_readfirstlane(node);

    const int beg = __builtin_amdgcn_readfirstlane(row_ptr[node]);
    const int end = __builtin_amdgcn_readfirstlane(row_ptr[node + 1]);

    float acc0 = 0.0f, acc1 = 0.0f;
    if (sub == 0) {
        const float dd = dinv[node];
        u32 sv = h[(size_t)node * 32 + lane32];
        float2 b = ((const float2*)bias)[lane32];
        acc0 = fmaf(bf_lo(sv) * dd, dd, b.x);
        acc1 = fmaf(bf_hi(sv) * dd, dd, b.y);
    }

    int j = beg;
    for (; j + 16 <= end; j += 16) {
        u32 ep[16];
#pragma unroll
        for (int k = 0; k < 16; ++k) ep[k] = ew[j + k];        // s_load (merged)
        u32 v[8]; float wl[8];
#pragma unroll
        for (int p = 0; p < 8; ++p) {
            u32 e0 = ep[2 * p], e1 = ep[2 * p + 1];
            u32 so = sub ? (e1 >> 15) : (e0 >> 15);            // cndmask
            wl[p]  = sub ? dec_w(e1) : dec_w(e0);              // cndmask
            v[p]   = h[((size_t)so << 5) + lane32];
        }
#pragma unroll
        for (int p = 0; p < 8; ++p) {
            acc0 = fmaf(wl[p], bf_lo(v[p]), acc0);
            acc1 = fmaf(wl[p], bf_hi(v[p]), acc1);
        }
    }
    for (; j < end; j += 8) {
        const int cnt = end - j;                               // 1..15 (SGPR)
        u32 ep[8];
#pragma unroll
        for (int k = 0; k < 8; ++k) {
            int c = j + k;
            ep[k] = ew[(c < end) ? c : end - 1];               // scalar clamp
        }
        u32 v[4]; float wl[4];
#pragma unroll
        for (int p = 0; p < 4; ++p) {
            u32 e0 = ep[2 * p], e1 = ep[2 * p + 1];
            float w0 = (2 * p     < cnt) ? dec_w(e0) : 0.0f;   // scalar select
            float w1 = (2 * p + 1 < cnt) ? dec_w(e1) : 0.0f;
            u32 so = sub ? (e1 >> 15) : (e0 >> 15);
            wl[p]  = sub ? w1 : w0;
            v[p]   = h[((size_t)so << 5) + lane32];            // pads: L1-hot row
        }
#pragma unroll
        for (int p = 0; p < 4; ++p) {
            acc0 = fmaf(wl[p], bf_lo(v[p]), acc0);
            acc1 = fmaf(wl[p], bf_hi(v[p]), acc1);
        }
    }

    acc0 += __shfl_xor(acc0, 32);
    acc1 += __shfl_xor(acc1, 32);
    if (sub == 0)
        ((float2*)(outp + (size_t)node * 64))[lane32] = make_float2(acc0, acc1);
}

extern "C" void kernel_launch(void* const* d_in, const int* in_sizes, int n_in,
                              void* d_out, int out_size, void* d_ws, size_t ws_size,
                              hipStream_t stream) {
    const float* x  = (const float*)d_in[0];
    const int*   ei = (const int*)d_in[1];
    const float* W1 = (const float*)d_in[2];
    const float* b1 = (const float*)d_in[3];
    const float* W2 = (const float*)d_in[4];
    const float* b2 = (const float*)d_in[5];
    float*       out = (float*)d_out;

    const int n = in_sizes[0] / 128;   // 100000
    const int E = in_sizes[1] / 2;     // 1600000
    const int* srcv = ei;
    const int* dstv = ei + E;

    const int NP = 102400;
    u32* wsd = (u32*)d_ws;
    float* dinv    = (float*)wsd;                        // NP
    int*   row_ptr = (int*)(wsd + NP);                   // NP
    u32*   ew      = wsd + 2 * (size_t)NP;               // E
    u32*   h1u     = ew + E;                             // n*64 (gemm1 C / gather in; LIVE through fused kernel)
    u32*   buf2    = h1u + (size_t)n * 64;               // n*64 (CSR scratch overlay, then h2)
    u32*   W1t     = buf2 + (size_t)n * 64;              // 8192
    u32*   W2t     = W1t + 8192;                         // 4096
    u32*   h2u     = buf2;                               // gemm2 C: n*32 (CSR scratch dead by then)

    // CSR scratch — overlaid on buf2 (dead once bucket_ew_gemm1 completes):
    int*   bco  = (int*)buf2;                            // M+1 (76,637)
    u32*   tmp2 = buf2 + 400000;                         // E
    int*   bsum = (int*)(buf2 + 2200000);                // 512

    const int NBIN = (n + 255) >> 8;          // 391 (bucket blocks, unchanged)
    const int NB3  = (E + 8191) / 8192;       // 196 (wide count/scatter blocks)
    const int M    = NBIN * NB3;              // 76,636
    const int MB   = (M + 1023) / 1024;       // 75

    const int gblocks = (n + 127) / 128;      // 782

    // --- CSR build (no global atomics) + fused gemm1 ---
    count_bins_pw<<<NB3 + 12, 1024, 0, stream>>>(dstv, bco, E, NBIN, NB3, M,
                                                 W1, W2, W1t, W2t);
    scan_reduce_g<<<MB, 1024, 0, stream>>>(bco, bsum, M);
    scan_apply_g2<<<MB, 1024, 0, stream>>>(bco, bsum, MB, M);
    scatter_bins<<<NB3, 1024, 0, stream>>>(srcv, dstv, bco, tmp2, E, NBIN, NB3);
    bucket_hist<<<NBIN, 256, 0, stream>>>(tmp2, bco, row_ptr, dinv, n, NB3, E);
    bucket_ew_gemm1<<<NBIN + gblocks, 256, 0, stream>>>(tmp2, bco, row_ptr, dinv,
                                                        ew, n, NB3, NBIN,
                                                        x, W1t, h1u);

    // --- fused layer-1 gather + layer-2 GEMM ---
    gather128_gemm2<<<(n + 31) / 32, 256, 0, stream>>>(h1u, dinv, row_ptr, ew,
                                                       b1, W2t, h2u, n);

    // --- layer-2 gather ---
    gather64<<<(n + 3) / 4, 256, 0, stream>>>(h2u, dinv, row_ptr, ew, b2, out, n);
}